// Round 1
// baseline (5263.804 us; speedup 1.0000x reference)
//
#include <hip/hip_runtime.h>

// ---------------------------------------------------------------------------
// RewardGNN: 2-layer GCN (256->128->64) + mean-pool + linear head.
// Baseline strategy: f32 throughout, scatter-add with global atomics.
// ---------------------------------------------------------------------------

static inline int ceil_div_ll(long long a, int b) { return (int)((a + b - 1) / b); }

__global__ void k_fill(float* __restrict__ p, int n, float v) {
    int i = blockIdx.x * blockDim.x + threadIdx.x;
    if (i < n) p[i] = v;
}

// deg[dst] += ew  (deg pre-filled with 1.0 for the self-loop)
__global__ void k_deg(const int* __restrict__ dst, const float* __restrict__ ew,
                      float* __restrict__ deg, int E) {
    int e = blockIdx.x * blockDim.x + threadIdx.x;
    if (e < E) atomicAdd(&deg[dst[e]], ew[e]);
}

// deg -> dinv in place
__global__ void k_rsqrt(float* __restrict__ d, int n) {
    int i = blockIdx.x * blockDim.x + threadIdx.x;
    if (i < n) {
        float v = d[i];
        d[i] = (v > 0.f) ? rsqrtf(v) : 0.f;
    }
}

// Y[n,ODIM] = X[n,KDIM] @ W[KDIM,ODIM].  blockDim = (ODIM/4, rows_per_block).
template <int KDIM, int ODIM>
__global__ void k_gemm(const float* __restrict__ X, const float* __restrict__ W,
                       float* __restrict__ Y, int n) {
    int jt  = threadIdx.x;                       // 0 .. ODIM/4-1
    int row = blockIdx.x * blockDim.y + threadIdx.y;
    if (row >= n) return;
    const float* xr = X + (size_t)row * KDIM;
    int j0 = jt * 4;
    float4 acc = make_float4(0.f, 0.f, 0.f, 0.f);
#pragma unroll 4
    for (int k = 0; k < KDIM; k += 4) {
        float4 xv = *(const float4*)(xr + k);
        float4 w0 = *(const float4*)(W + (size_t)(k + 0) * ODIM + j0);
        float4 w1 = *(const float4*)(W + (size_t)(k + 1) * ODIM + j0);
        float4 w2 = *(const float4*)(W + (size_t)(k + 2) * ODIM + j0);
        float4 w3 = *(const float4*)(W + (size_t)(k + 3) * ODIM + j0);
        acc.x += xv.x * w0.x + xv.y * w1.x + xv.z * w2.x + xv.w * w3.x;
        acc.y += xv.x * w0.y + xv.y * w1.y + xv.z * w2.y + xv.w * w3.y;
        acc.z += xv.x * w0.z + xv.y * w1.z + xv.z * w2.z + xv.w * w3.z;
        acc.w += xv.x * w0.w + xv.y * w1.w + xv.z * w2.w + xv.w * w3.w;
    }
    *(float4*)(Y + (size_t)row * ODIM + j0) = acc;
}

// h[i,:] = xw[i,:] * dinv[i]^2   (self-loop term; pure overwrite -> also inits h)
template <int F>
__global__ void k_selfloop(const float* __restrict__ xw, const float* __restrict__ dinv,
                           float* __restrict__ h, int n) {
    const int CPE = F / 4;
    int t = blockIdx.x * blockDim.x + threadIdx.x;
    if (t >= n * CPE) return;
    int i = t / CPE, c = t % CPE;
    float dv = dinv[i];
    float s  = dv * dv;
    float4 v = *(const float4*)(xw + (size_t)i * F + c * 4);
    v.x *= s; v.y *= s; v.z *= s; v.w *= s;
    *(float4*)(h + (size_t)i * F + c * 4) = v;
}

// h[dst,:] += xw[src,:] * (dinv[src]*ew*dinv[dst])   one thread = one float4 chunk
template <int F>
__global__ void k_scatter(const int* __restrict__ src, const int* __restrict__ dst,
                          const float* __restrict__ ew, const float* __restrict__ dinv,
                          const float* __restrict__ xw, float* __restrict__ h, int E) {
    const int CPE = F / 4;
    long long t = (long long)blockIdx.x * blockDim.x + threadIdx.x;
    if (t >= (long long)E * CPE) return;
    int e = (int)(t / CPE), c = (int)(t % CPE);
    int s = src[e], d = dst[e];
    float coef = dinv[s] * ew[e] * dinv[d];
    float4 v = *(const float4*)(xw + (size_t)s * F + c * 4);
    float* hp = h + (size_t)d * F + c * 4;
    atomicAdd(hp + 0, v.x * coef);
    atomicAdd(hp + 1, v.y * coef);
    atomicAdd(hp + 2, v.z * coef);
    atomicAdd(hp + 3, v.w * coef);
}

// h = relu(h + b)
template <int F>
__global__ void k_biasrelu(float* __restrict__ h, const float* __restrict__ b, int n) {
    const int CPE = F / 4;
    int t = blockIdx.x * blockDim.x + threadIdx.x;
    if (t >= n * CPE) return;
    int i = t / CPE, c = t % CPE;
    float4 v  = *(float4*)(h + (size_t)i * F + c * 4);
    float4 bb = *(const float4*)(b + c * 4);
    v.x = fmaxf(v.x + bb.x, 0.f);
    v.y = fmaxf(v.y + bb.y, 0.f);
    v.z = fmaxf(v.z + bb.z, 0.f);
    v.w = fmaxf(v.w + bb.w, 0.f);
    *(float4*)(h + (size_t)i * F + c * 4) = v;
}

// sums[batch[i], f] += h2[i, f]; cnt[batch[i]] += 1
__global__ void k_pool(const float* __restrict__ h2, const int* __restrict__ batch,
                       float* __restrict__ sums, float* __restrict__ cnt, int n) {
    long long t = (long long)blockIdx.x * blockDim.x + threadIdx.x;
    if (t >= (long long)n * 64) return;
    int i = (int)(t >> 6), f = (int)(t & 63);
    int g = batch[i];
    atomicAdd(&sums[g * 64 + f], h2[(size_t)i * 64 + f]);
    if (f == 0) atomicAdd(&cnt[g], 1.0f);
}

// out[g] = dot(sums[g]/max(cnt,1), Wfc) + bfc   (one wave per graph)
__global__ void k_final(const float* __restrict__ sums, const float* __restrict__ cnt,
                        const float* __restrict__ Wfc, const float* __restrict__ bfc,
                        float* __restrict__ out) {
    int g = blockIdx.x;
    int f = threadIdx.x;  // 64 threads = 1 wave
    float v = sums[g * 64 + f] * Wfc[f];
#pragma unroll
    for (int o = 32; o > 0; o >>= 1) v += __shfl_down(v, o);
    if (f == 0) {
        float c = fmaxf(cnt[g], 1.0f);
        out[g] = v / c + bfc[0];
    }
}

extern "C" void kernel_launch(void* const* d_in, const int* in_sizes, int n_in,
                              void* d_out, int out_size, void* d_ws, size_t ws_size,
                              hipStream_t stream) {
    const float* x    = (const float*)d_in[0];
    const int*   ei   = (const int*)d_in[1];    // [2, E]
    const float* ew   = (const float*)d_in[2];  // [E]
    const int*   bat  = (const int*)d_in[3];    // [N]
    const float* W1   = (const float*)d_in[4];  // [256,128]
    const float* b1   = (const float*)d_in[5];
    const float* W2   = (const float*)d_in[6];  // [128,64]
    const float* b2   = (const float*)d_in[7];
    const float* Wfc  = (const float*)d_in[8];  // [64,1]
    const float* bfc  = (const float*)d_in[9];
    float*       out  = (float*)d_out;          // [G,1] fp32

    const int N = in_sizes[0] / 256;
    const int E = in_sizes[2];
    const int G = out_size;

    const int* src = ei;
    const int* dst = ei + E;

    // workspace layout (f32)
    float* deg  = (float*)d_ws;            // N  (becomes dinv in place)
    float* bufA = deg + ((N + 3) & ~3);    // N*128 : xw1, later xw2
    float* bufB = bufA + (size_t)N * 128;  // N*128 : h1, later h2
    float* sums = bufB + (size_t)N * 128;  // G*64
    float* cnt  = sums + (size_t)G * 64;   // G

    const int B = 256;

    // 1) degree (self-loop weight 1.0 pre-filled) -> dinv
    k_fill<<<ceil_div_ll(N, B), B, 0, stream>>>(deg, N, 1.0f);
    k_deg<<<ceil_div_ll(E, B), B, 0, stream>>>(dst, ew, deg, E);
    k_rsqrt<<<ceil_div_ll(N, B), B, 0, stream>>>(deg, N);

    // 2) layer 1: xw1 = x @ W1
    {
        dim3 blk(32, 8);  // 128/4 j-threads, 8 rows
        k_gemm<256, 128><<<ceil_div_ll(N, 8), blk, 0, stream>>>(x, W1, bufA, N);
    }
    k_selfloop<128><<<ceil_div_ll((long long)N * 32, B), B, 0, stream>>>(bufA, deg, bufB, N);
    k_scatter<128><<<ceil_div_ll((long long)E * 32, B), B, 0, stream>>>(src, dst, ew, deg, bufA, bufB, E);
    k_biasrelu<128><<<ceil_div_ll((long long)N * 32, B), B, 0, stream>>>(bufB, b1, N);

    // 3) layer 2: xw2 = h1 @ W2
    {
        dim3 blk(16, 16);  // 64/4 j-threads, 16 rows
        k_gemm<128, 64><<<ceil_div_ll(N, 16), blk, 0, stream>>>(bufB, W2, bufA, N);
    }
    k_selfloop<64><<<ceil_div_ll((long long)N * 16, B), B, 0, stream>>>(bufA, deg, bufB, N);
    k_scatter<64><<<ceil_div_ll((long long)E * 16, B), B, 0, stream>>>(src, dst, ew, deg, bufA, bufB, E);
    k_biasrelu<64><<<ceil_div_ll((long long)N * 16, B), B, 0, stream>>>(bufB, b2, N);

    // 4) mean-pool + head
    k_fill<<<ceil_div_ll(G * 64 + G, B), B, 0, stream>>>(sums, G * 64 + G, 0.0f);  // sums and cnt contiguous
    k_pool<<<ceil_div_ll((long long)N * 64, B), B, 0, stream>>>(bufB, bat, sums, cnt, N);
    k_final<<<G, 64, 0, stream>>>(sums, cnt, Wfc, bfc, out);
}

// Round 2
// 1952.088 us; speedup vs baseline: 2.6965x; 2.6965x over previous
//
#include <hip/hip_runtime.h>

// ---------------------------------------------------------------------------
// RewardGNN: 2-layer GCN (256->128->64) + mean-pool + linear head.
// Round 2: scatter->gather via per-call CSR build (counting sort).
//   - no f32 atomics in the hot path (was 307M atomics = 3.9ms)
//   - gather: one wave per dst node, edges accumulated in registers
//   - bias+relu fused into gather; layer-2 gather also fuses mean-pool
// ---------------------------------------------------------------------------

static inline int ceil_div_ll(long long a, int b) { return (int)((a + b - 1) / b); }

__global__ void k_fill(float* __restrict__ p, int n, float v) {
    int i = blockIdx.x * blockDim.x + threadIdx.x;
    if (i < n) p[i] = v;
}

__global__ void k_zero_i(int* __restrict__ p, int n) {
    int i = blockIdx.x * blockDim.x + threadIdx.x;
    if (i < n) p[i] = 0;
}

// deg[dst] += ew (deg pre-filled 1.0 for self-loop); count[dst] += 1
__global__ void k_deg_count(const int* __restrict__ dst, const float* __restrict__ ew,
                            float* __restrict__ deg, int* __restrict__ count, int E) {
    int e = blockIdx.x * blockDim.x + threadIdx.x;
    if (e < E) {
        int d = dst[e];
        atomicAdd(&deg[d], ew[e]);
        atomicAdd(&count[d], 1);
    }
}

__global__ void k_rsqrt(float* __restrict__ d, int n) {
    int i = blockIdx.x * blockDim.x + threadIdx.x;
    if (i < n) {
        float v = d[i];
        d[i] = (v > 0.f) ? rsqrtf(v) : 0.f;
    }
}

// Single-workgroup chunked exclusive scan of count[0..n) -> rowptr[0..n].
// Overwrites count[i] with the running offset (count doubles as the fill cursor).
__global__ void k_scan(int* __restrict__ count, int* __restrict__ rowptr, int n) {
    const int T = 256;
    __shared__ int lds[T];
    int t = threadIdx.x;
    int chunk = (n + T - 1) / T;
    int lo = t * chunk, hi = min(lo + chunk, n);
    int s = 0;
    for (int i = lo; i < hi; ++i) s += count[i];
    lds[t] = s;
    for (int off = 1; off < T; off <<= 1) {
        __syncthreads();
        int tmp = (t >= off) ? lds[t - off] : 0;
        __syncthreads();
        lds[t] += tmp;
    }
    __syncthreads();
    int run = lds[t] - s;  // exclusive base for this chunk
    for (int i = lo; i < hi; ++i) {
        int c = count[i];
        rowptr[i] = run;
        count[i] = run;  // cursor init
        run += c;
    }
    if (t == T - 1) rowptr[n] = run;
}

// Fill CSR: per edge, append (src, coef) at cursor[dst]++
__global__ void k_csr_fill(const int* __restrict__ src, const int* __restrict__ dst,
                           const float* __restrict__ ew, const float* __restrict__ dinv,
                           int* __restrict__ cursor, int* __restrict__ csr_src,
                           float* __restrict__ csr_coef, int E) {
    int e = blockIdx.x * blockDim.x + threadIdx.x;
    if (e < E) {
        int s = src[e], d = dst[e];
        int pos = atomicAdd(&cursor[d], 1);
        csr_src[pos]  = s;
        csr_coef[pos] = dinv[s] * ew[e] * dinv[d];
    }
}

// Y[n,ODIM] = X[n,KDIM] @ W[KDIM,ODIM].  blockDim = (ODIM/4, rows_per_block).
template <int KDIM, int ODIM>
__global__ void k_gemm(const float* __restrict__ X, const float* __restrict__ W,
                       float* __restrict__ Y, int n) {
    int jt  = threadIdx.x;
    int row = blockIdx.x * blockDim.y + threadIdx.y;
    if (row >= n) return;
    const float* xr = X + (size_t)row * KDIM;
    int j0 = jt * 4;
    float4 acc = make_float4(0.f, 0.f, 0.f, 0.f);
#pragma unroll 4
    for (int k = 0; k < KDIM; k += 4) {
        float4 xv = *(const float4*)(xr + k);
        float4 w0 = *(const float4*)(W + (size_t)(k + 0) * ODIM + j0);
        float4 w1 = *(const float4*)(W + (size_t)(k + 1) * ODIM + j0);
        float4 w2 = *(const float4*)(W + (size_t)(k + 2) * ODIM + j0);
        float4 w3 = *(const float4*)(W + (size_t)(k + 3) * ODIM + j0);
        acc.x += xv.x * w0.x + xv.y * w1.x + xv.z * w2.x + xv.w * w3.x;
        acc.y += xv.x * w0.y + xv.y * w1.y + xv.z * w2.y + xv.w * w3.y;
        acc.z += xv.x * w0.z + xv.y * w1.z + xv.z * w2.z + xv.w * w3.z;
        acc.w += xv.x * w0.w + xv.y * w1.w + xv.z * w2.w + xv.w * w3.w;
    }
    *(float4*)(Y + (size_t)row * ODIM + j0) = acc;
}

// Gather layer: one wave per dst node.
//   out_row = relu( dinv[i]^2 * xw[i] + sum_e coef*xw[src_e] + bias )
// F=128: lane holds float2; F=64: lane holds 1 float.
// POOL: instead of writing out, atomically add into sums[batch[i]] (+cnt).
template <int F, bool POOL>
__global__ void k_gather(const float* __restrict__ xw, const int* __restrict__ rowptr,
                         const int* __restrict__ csr_src, const float* __restrict__ csr_coef,
                         const float* __restrict__ dinv, const float* __restrict__ bias,
                         float* __restrict__ out, const int* __restrict__ batch,
                         float* __restrict__ sums, float* __restrict__ cnt, int n) {
    int wave = threadIdx.x >> 6;
    int lane = threadIdx.x & 63;
    int i = blockIdx.x * 4 + wave;
    if (i >= n) return;

    float dv = dinv[i];
    float sl = dv * dv;
    int e0 = rowptr[i], e1 = rowptr[i + 1];

    if constexpr (F == 128) {
        const float2* xr = (const float2*)(xw + (size_t)i * F) + lane;
        float2 acc = *xr;
        acc.x *= sl; acc.y *= sl;
        for (int e = e0; e < e1; ++e) {
            int s  = csr_src[e];
            float c = csr_coef[e];
            float2 v = *((const float2*)(xw + (size_t)s * F) + lane);
            acc.x += c * v.x;
            acc.y += c * v.y;
        }
        float2 bb = *((const float2*)bias + lane);
        acc.x = fmaxf(acc.x + bb.x, 0.f);
        acc.y = fmaxf(acc.y + bb.y, 0.f);
        *((float2*)(out + (size_t)i * F) + lane) = acc;
    } else {  // F == 64
        float acc = xw[(size_t)i * F + lane] * sl;
        for (int e = e0; e < e1; ++e) {
            int s  = csr_src[e];
            float c = csr_coef[e];
            acc += c * xw[(size_t)s * F + lane];
        }
        acc = fmaxf(acc + bias[lane], 0.f);
        if constexpr (POOL) {
            int g = batch[i];
            atomicAdd(&sums[g * 64 + lane], acc);
            if (lane == 0) atomicAdd(&cnt[g], 1.0f);
        } else {
            out[(size_t)i * F + lane] = acc;
        }
    }
}

// out[g] = dot(sums[g]/max(cnt,1), Wfc) + bfc   (one wave per graph)
__global__ void k_final(const float* __restrict__ sums, const float* __restrict__ cnt,
                        const float* __restrict__ Wfc, const float* __restrict__ bfc,
                        float* __restrict__ out) {
    int g = blockIdx.x;
    int f = threadIdx.x;
    float v = sums[g * 64 + f] * Wfc[f];
#pragma unroll
    for (int o = 32; o > 0; o >>= 1) v += __shfl_down(v, o);
    if (f == 0) {
        float c = fmaxf(cnt[g], 1.0f);
        out[g] = v / c + bfc[0];
    }
}

extern "C" void kernel_launch(void* const* d_in, const int* in_sizes, int n_in,
                              void* d_out, int out_size, void* d_ws, size_t ws_size,
                              hipStream_t stream) {
    const float* x    = (const float*)d_in[0];
    const int*   ei   = (const int*)d_in[1];    // [2, E]
    const float* ew   = (const float*)d_in[2];  // [E]
    const int*   bat  = (const int*)d_in[3];    // [N]
    const float* W1   = (const float*)d_in[4];  // [256,128]
    const float* b1   = (const float*)d_in[5];
    const float* W2   = (const float*)d_in[6];  // [128,64]
    const float* b2   = (const float*)d_in[7];
    const float* Wfc  = (const float*)d_in[8];  // [64,1]
    const float* bfc  = (const float*)d_in[9];
    float*       out  = (float*)d_out;          // [G,1] fp32

    const int N = in_sizes[0] / 256;
    const int E = in_sizes[2];
    const int G = out_size;

    const int* src = ei;
    const int* dst = ei + E;

    // workspace layout
    const int Npad = (N + 4) & ~3;
    float* deg      = (float*)d_ws;                 // N (-> dinv in place)
    int*   count    = (int*)(deg + Npad);           // N (-> cursor after scan)
    int*   rowptr   = count + Npad;                 // N+1
    int*   csr_src  = rowptr + Npad;                // E
    float* csr_coef = (float*)(csr_src + E);        // E
    float* bufA     = csr_coef + E;                 // N*128 : xw1, later xw2
    float* bufB     = bufA + (size_t)N * 128;       // N*128 : h1
    float* sums     = bufB + (size_t)N * 128;       // G*64
    float* cnt      = sums + (size_t)G * 64;        // G

    const int B = 256;

    // 1) degree + in-degree count
    k_fill<<<ceil_div_ll(N, B), B, 0, stream>>>(deg, N, 1.0f);
    k_zero_i<<<ceil_div_ll(N, B), B, 0, stream>>>(count, N);
    k_deg_count<<<ceil_div_ll(E, B), B, 0, stream>>>(dst, ew, deg, count, E);
    k_rsqrt<<<ceil_div_ll(N, B), B, 0, stream>>>(deg, N);

    // 2) CSR build (counting sort by dst)
    k_scan<<<1, 256, 0, stream>>>(count, rowptr, N);
    k_csr_fill<<<ceil_div_ll(E, B), B, 0, stream>>>(src, dst, ew, deg, count,
                                                    csr_src, csr_coef, E);

    // 3) layer 1: xw1 = x @ W1 ; h1 = relu(gather + b1)
    {
        dim3 blk(32, 8);
        k_gemm<256, 128><<<ceil_div_ll(N, 8), blk, 0, stream>>>(x, W1, bufA, N);
    }
    k_gather<128, false><<<ceil_div_ll(N, 4), 256, 0, stream>>>(
        bufA, rowptr, csr_src, csr_coef, deg, b1, bufB, nullptr, nullptr, nullptr, N);

    // 4) layer 2: xw2 = h1 @ W2 ; pooled sums = relu(gather + b2) grouped by batch
    {
        dim3 blk(16, 16);
        k_gemm<128, 64><<<ceil_div_ll(N, 16), blk, 0, stream>>>(bufB, W2, bufA, N);
    }
    k_fill<<<ceil_div_ll(G * 64 + G, B), B, 0, stream>>>(sums, G * 64 + G, 0.0f);
    k_gather<64, true><<<ceil_div_ll(N, 4), 256, 0, stream>>>(
        bufA, rowptr, csr_src, csr_coef, deg, b2, nullptr, bat, sums, cnt, N);

    // 5) head
    k_final<<<G, 64, 0, stream>>>(sums, cnt, Wfc, bfc, out);
}

// Round 3
// 982.424 us; speedup vs baseline: 5.3580x; 1.9870x over previous
//
#include <hip/hip_runtime.h>

// ---------------------------------------------------------------------------
// RewardGNN: 2-layer GCN (256->128->64) + mean-pool + linear head.
// Round 3:
//   - gather: 8-deep MLP unroll, scalar (s_load) edge metadata
//   - gemm: LDS x-tile + 4x4 register blocking
//   - pool+head fused, no atomics (batch is sorted -> binary search ranges)
// ---------------------------------------------------------------------------

static inline int ceil_div_ll(long long a, int b) { return (int)((a + b - 1) / b); }

__global__ void k_fill(float* __restrict__ p, int n, float v) {
    int i = blockIdx.x * blockDim.x + threadIdx.x;
    if (i < n) p[i] = v;
}

__global__ void k_zero_i(int* __restrict__ p, int n) {
    int i = blockIdx.x * blockDim.x + threadIdx.x;
    if (i < n) p[i] = 0;
}

// deg[dst] += ew (deg pre-filled 1.0 for self-loop); count[dst] += 1
__global__ void k_deg_count(const int* __restrict__ dst, const float* __restrict__ ew,
                            float* __restrict__ deg, int* __restrict__ count, int E) {
    int e = blockIdx.x * blockDim.x + threadIdx.x;
    if (e < E) {
        int d = dst[e];
        atomicAdd(&deg[d], ew[e]);
        atomicAdd(&count[d], 1);
    }
}

__global__ void k_rsqrt(float* __restrict__ d, int n) {
    int i = blockIdx.x * blockDim.x + threadIdx.x;
    if (i < n) {
        float v = d[i];
        d[i] = (v > 0.f) ? rsqrtf(v) : 0.f;
    }
}

// Single-workgroup chunked exclusive scan of count[0..n) -> rowptr[0..n].
// Overwrites count[i] with the running offset (count doubles as the fill cursor).
__global__ void k_scan(int* __restrict__ count, int* __restrict__ rowptr, int n) {
    const int T = 256;
    __shared__ int lds[T];
    int t = threadIdx.x;
    int chunk = (n + T - 1) / T;
    int lo = t * chunk, hi = min(lo + chunk, n);
    int s = 0;
    for (int i = lo; i < hi; ++i) s += count[i];
    lds[t] = s;
    for (int off = 1; off < T; off <<= 1) {
        __syncthreads();
        int tmp = (t >= off) ? lds[t - off] : 0;
        __syncthreads();
        lds[t] += tmp;
    }
    __syncthreads();
    int run = lds[t] - s;  // exclusive base for this chunk
    for (int i = lo; i < hi; ++i) {
        int c = count[i];
        rowptr[i] = run;
        count[i] = run;  // cursor init
        run += c;
    }
    if (t == T - 1) rowptr[n] = run;
}

// Fill CSR: per edge, append (src, coef) at cursor[dst]++
__global__ void k_csr_fill(const int* __restrict__ src, const int* __restrict__ dst,
                           const float* __restrict__ ew, const float* __restrict__ dinv,
                           int* __restrict__ cursor, int* __restrict__ csr_src,
                           float* __restrict__ csr_coef, int E) {
    int e = blockIdx.x * blockDim.x + threadIdx.x;
    if (e < E) {
        int s = src[e], d = dst[e];
        int pos = atomicAdd(&cursor[d], 1);
        csr_src[pos]  = s;
        csr_coef[pos] = dinv[s] * ew[e] * dinv[d];
    }
}

// ---------------------------------------------------------------------------
// GEMM: Y[n,ODIM] = X[n,KDIM] @ W[KDIM,ODIM]
// 256 threads; x-tile staged in padded LDS; each thread computes 4 rows x 4 cols.
// ---------------------------------------------------------------------------
template <int KDIM, int ODIM>
__global__ void k_gemm(const float* __restrict__ X, const float* __restrict__ W,
                       float* __restrict__ Y, int n) {
    constexpr int JT   = ODIM / 4;   // threads along j
    constexpr int RY   = 256 / JT;   // row groups
    constexpr int TM   = RY * 4;     // rows per block
    constexpr int LSTR = KDIM + 4;   // padded floats per LDS row
    __shared__ float xs[TM * LSTR];

    int tid = threadIdx.x;
    int rowbase = blockIdx.x * TM;

    // stage x-tile
    for (int idx = tid; idx < TM * (KDIM / 4); idx += 256) {
        int r = idx / (KDIM / 4), c4 = idx % (KDIM / 4);
        int row = rowbase + r;
        float4 v = (row < n) ? *(const float4*)(X + (size_t)row * KDIM + c4 * 4)
                             : make_float4(0.f, 0.f, 0.f, 0.f);
        *(float4*)(xs + r * LSTR + c4 * 4) = v;
    }
    __syncthreads();

    int jt = tid % JT, ry = tid / JT;
    int j0 = jt * 4;
    int r0 = ry * 4;

    float4 acc[4];
#pragma unroll
    for (int r = 0; r < 4; ++r) acc[r] = make_float4(0.f, 0.f, 0.f, 0.f);

    for (int k4 = 0; k4 < KDIM / 4; ++k4) {
        const float* wb = W + (size_t)(k4 * 4) * ODIM + j0;
        float4 w0 = *(const float4*)(wb + 0 * ODIM);
        float4 w1 = *(const float4*)(wb + 1 * ODIM);
        float4 w2 = *(const float4*)(wb + 2 * ODIM);
        float4 w3 = *(const float4*)(wb + 3 * ODIM);
#pragma unroll
        for (int r = 0; r < 4; ++r) {
            float4 xv = *(const float4*)(xs + (r0 + r) * LSTR + k4 * 4);
            acc[r].x += xv.x * w0.x + xv.y * w1.x + xv.z * w2.x + xv.w * w3.x;
            acc[r].y += xv.x * w0.y + xv.y * w1.y + xv.z * w2.y + xv.w * w3.y;
            acc[r].z += xv.x * w0.z + xv.y * w1.z + xv.z * w2.z + xv.w * w3.z;
            acc[r].w += xv.x * w0.w + xv.y * w1.w + xv.z * w2.w + xv.w * w3.w;
        }
    }

#pragma unroll
    for (int r = 0; r < 4; ++r) {
        int row = rowbase + r0 + r;
        if (row < n) *(float4*)(Y + (size_t)row * ODIM + j0) = acc[r];
    }
}

// ---------------------------------------------------------------------------
// Gather: out[i] = relu( dinv[i]^2 * xw[i] + sum_e coef_e * xw[src_e] + bias )
// One wave per node. 8-deep unroll for memory-level parallelism.
// ---------------------------------------------------------------------------
template <int F>
__global__ void k_gather(const float* __restrict__ xw, const int* __restrict__ rowptr,
                         const int* __restrict__ csr_src, const float* __restrict__ csr_coef,
                         const float* __restrict__ dinv, const float* __restrict__ bias,
                         float* __restrict__ out, int n) {
    int wave = threadIdx.x >> 6;
    int lane = threadIdx.x & 63;
    int i = blockIdx.x * 4 + wave;
    if (i >= n) return;

    float dv = dinv[i];
    float sl = dv * dv;
    int e0 = __builtin_amdgcn_readfirstlane(rowptr[i]);
    int e1 = __builtin_amdgcn_readfirstlane(rowptr[i + 1]);

    if constexpr (F == 128) {
        const float2* base = (const float2*)xw;  // row stride = 64 float2
        float2 a0 = base[(size_t)i * 64 + lane];
        a0.x *= sl; a0.y *= sl;
        float2 a1 = make_float2(0.f, 0.f);
        float2 a2 = make_float2(0.f, 0.f);
        float2 a3 = make_float2(0.f, 0.f);
        int e = e0;
        for (; e + 8 <= e1; e += 8) {
            int s0 = csr_src[e + 0], s1 = csr_src[e + 1], s2 = csr_src[e + 2], s3 = csr_src[e + 3];
            int s4 = csr_src[e + 4], s5 = csr_src[e + 5], s6 = csr_src[e + 6], s7 = csr_src[e + 7];
            float c0 = csr_coef[e + 0], c1 = csr_coef[e + 1], c2 = csr_coef[e + 2], c3 = csr_coef[e + 3];
            float c4 = csr_coef[e + 4], c5 = csr_coef[e + 5], c6 = csr_coef[e + 6], c7 = csr_coef[e + 7];
            float2 v0 = base[(size_t)s0 * 64 + lane];
            float2 v1 = base[(size_t)s1 * 64 + lane];
            float2 v2 = base[(size_t)s2 * 64 + lane];
            float2 v3 = base[(size_t)s3 * 64 + lane];
            float2 v4 = base[(size_t)s4 * 64 + lane];
            float2 v5 = base[(size_t)s5 * 64 + lane];
            float2 v6 = base[(size_t)s6 * 64 + lane];
            float2 v7 = base[(size_t)s7 * 64 + lane];
            a0.x += c0 * v0.x; a0.y += c0 * v0.y;
            a1.x += c1 * v1.x; a1.y += c1 * v1.y;
            a2.x += c2 * v2.x; a2.y += c2 * v2.y;
            a3.x += c3 * v3.x; a3.y += c3 * v3.y;
            a0.x += c4 * v4.x; a0.y += c4 * v4.y;
            a1.x += c5 * v5.x; a1.y += c5 * v5.y;
            a2.x += c6 * v6.x; a2.y += c6 * v6.y;
            a3.x += c7 * v7.x; a3.y += c7 * v7.y;
        }
        for (; e + 2 <= e1; e += 2) {
            int s0 = csr_src[e + 0], s1 = csr_src[e + 1];
            float c0 = csr_coef[e + 0], c1 = csr_coef[e + 1];
            float2 v0 = base[(size_t)s0 * 64 + lane];
            float2 v1 = base[(size_t)s1 * 64 + lane];
            a0.x += c0 * v0.x; a0.y += c0 * v0.y;
            a1.x += c1 * v1.x; a1.y += c1 * v1.y;
        }
        if (e < e1) {
            int s0 = csr_src[e];
            float c0 = csr_coef[e];
            float2 v0 = base[(size_t)s0 * 64 + lane];
            a0.x += c0 * v0.x; a0.y += c0 * v0.y;
        }
        float2 bb = *((const float2*)bias + lane);
        float rx = fmaxf((a0.x + a1.x) + (a2.x + a3.x) + bb.x, 0.f);
        float ry = fmaxf((a0.y + a1.y) + (a2.y + a3.y) + bb.y, 0.f);
        float2 res = make_float2(rx, ry);
        *((float2*)(out + (size_t)i * F) + lane) = res;
    } else {  // F == 64, one float per lane
        float a0 = xw[(size_t)i * 64 + lane] * sl;
        float a1 = 0.f, a2 = 0.f, a3 = 0.f;
        int e = e0;
        for (; e + 8 <= e1; e += 8) {
            int s0 = csr_src[e + 0], s1 = csr_src[e + 1], s2 = csr_src[e + 2], s3 = csr_src[e + 3];
            int s4 = csr_src[e + 4], s5 = csr_src[e + 5], s6 = csr_src[e + 6], s7 = csr_src[e + 7];
            float c0 = csr_coef[e + 0], c1 = csr_coef[e + 1], c2 = csr_coef[e + 2], c3 = csr_coef[e + 3];
            float c4 = csr_coef[e + 4], c5 = csr_coef[e + 5], c6 = csr_coef[e + 6], c7 = csr_coef[e + 7];
            float v0 = xw[(size_t)s0 * 64 + lane];
            float v1 = xw[(size_t)s1 * 64 + lane];
            float v2 = xw[(size_t)s2 * 64 + lane];
            float v3 = xw[(size_t)s3 * 64 + lane];
            float v4 = xw[(size_t)s4 * 64 + lane];
            float v5 = xw[(size_t)s5 * 64 + lane];
            float v6 = xw[(size_t)s6 * 64 + lane];
            float v7 = xw[(size_t)s7 * 64 + lane];
            a0 += c0 * v0; a1 += c1 * v1; a2 += c2 * v2; a3 += c3 * v3;
            a0 += c4 * v4; a1 += c5 * v5; a2 += c6 * v6; a3 += c7 * v7;
        }
        for (; e + 2 <= e1; e += 2) {
            int s0 = csr_src[e + 0], s1 = csr_src[e + 1];
            float c0 = csr_coef[e + 0], c1 = csr_coef[e + 1];
            a0 += c0 * xw[(size_t)s0 * 64 + lane];
            a1 += c1 * xw[(size_t)s1 * 64 + lane];
        }
        if (e < e1) {
            a0 += csr_coef[e] * xw[(size_t)csr_src[e] * 64 + lane];
        }
        float res = fmaxf((a0 + a1) + (a2 + a3) + bias[lane], 0.f);
        out[(size_t)i * 64 + lane] = res;
    }
}

// ---------------------------------------------------------------------------
// Fused mean-pool + head: one block per graph (batch is sorted).
// out[g] = dot(mean(h2[lo:hi]), Wfc) + bfc
// ---------------------------------------------------------------------------
__global__ void k_pool_head(const float* __restrict__ h2, const int* __restrict__ batch,
                            const float* __restrict__ Wfc, const float* __restrict__ bfc,
                            float* __restrict__ out, int n) {
    int g = blockIdx.x;
    __shared__ int bounds[2];
    __shared__ float part[256];
    int t = threadIdx.x;
    if (t < 2) {
        int target = g + t;  // lower_bound(batch, target)
        int lo = 0, hi = n;
        while (lo < hi) {
            int mid = (lo + hi) >> 1;
            if (batch[mid] < target) lo = mid + 1; else hi = mid;
        }
        bounds[t] = lo;
    }
    __syncthreads();
    int lo = bounds[0], hi = bounds[1];
    int f = t & 63, rg = t >> 6;  // 4 row groups
    float acc = 0.f;
    for (int r = lo + rg; r < hi; r += 4) acc += h2[(size_t)r * 64 + f];
    part[t] = acc;
    __syncthreads();
    if (t < 64) {
        float s = part[t] + part[t + 64] + part[t + 128] + part[t + 192];
        float cntf = (float)(hi - lo);
        float v = (s / fmaxf(cntf, 1.0f)) * Wfc[f];
#pragma unroll
        for (int o = 32; o > 0; o >>= 1) v += __shfl_down(v, o);
        if (t == 0) out[g] = v + bfc[0];
    }
}

extern "C" void kernel_launch(void* const* d_in, const int* in_sizes, int n_in,
                              void* d_out, int out_size, void* d_ws, size_t ws_size,
                              hipStream_t stream) {
    const float* x    = (const float*)d_in[0];
    const int*   ei   = (const int*)d_in[1];    // [2, E]
    const float* ew   = (const float*)d_in[2];  // [E]
    const int*   bat  = (const int*)d_in[3];    // [N]
    const float* W1   = (const float*)d_in[4];  // [256,128]
    const float* b1   = (const float*)d_in[5];
    const float* W2   = (const float*)d_in[6];  // [128,64]
    const float* b2   = (const float*)d_in[7];
    const float* Wfc  = (const float*)d_in[8];  // [64,1]
    const float* bfc  = (const float*)d_in[9];
    float*       out  = (float*)d_out;          // [G,1] fp32

    const int N = in_sizes[0] / 256;
    const int E = in_sizes[2];
    const int G = out_size;

    const int* src = ei;
    const int* dst = ei + E;

    // workspace layout
    const int Npad = (N + 4) & ~3;
    float* deg      = (float*)d_ws;                 // N (-> dinv in place)
    int*   count    = (int*)(deg + Npad);           // N (-> cursor after scan)
    int*   rowptr   = count + Npad;                 // N+1
    int*   csr_src  = rowptr + Npad;                // E
    float* csr_coef = (float*)(csr_src + E);        // E
    float* bufA     = csr_coef + E;                 // N*128 : xw1, later xw2
    float* bufB     = bufA + (size_t)N * 128;       // N*128 : h1, later h2

    const int B = 256;

    // 1) degree + in-degree count
    k_fill<<<ceil_div_ll(N, B), B, 0, stream>>>(deg, N, 1.0f);
    k_zero_i<<<ceil_div_ll(N, B), B, 0, stream>>>(count, N);
    k_deg_count<<<ceil_div_ll(E, B), B, 0, stream>>>(dst, ew, deg, count, E);
    k_rsqrt<<<ceil_div_ll(N, B), B, 0, stream>>>(deg, N);

    // 2) CSR build (counting sort by dst)
    k_scan<<<1, 256, 0, stream>>>(count, rowptr, N);
    k_csr_fill<<<ceil_div_ll(E, B), B, 0, stream>>>(src, dst, ew, deg, count,
                                                    csr_src, csr_coef, E);

    // 3) layer 1: xw1 = x @ W1 ; h1 = relu(gather + b1)
    k_gemm<256, 128><<<ceil_div_ll(N, 32), 256, 0, stream>>>(x, W1, bufA, N);
    k_gather<128><<<ceil_div_ll(N, 4), 256, 0, stream>>>(
        bufA, rowptr, csr_src, csr_coef, deg, b1, bufB, N);

    // 4) layer 2: xw2 = h1 @ W2 ; h2 = relu(gather + b2)
    k_gemm<128, 64><<<ceil_div_ll(N, 64), 256, 0, stream>>>(bufB, W2, bufA, N);
    k_gather<64><<<ceil_div_ll(N, 4), 256, 0, stream>>>(
        bufA, rowptr, csr_src, csr_coef, deg, b2, bufB, N);

    // 5) fused mean-pool + head
    k_pool_head<<<G, 256, 0, stream>>>(bufB, bat, Wfc, bfc, out, N);
}

// Round 4
// 774.917 us; speedup vs baseline: 6.7927x; 1.2678x over previous
//
#include <hip/hip_runtime.h>

// ---------------------------------------------------------------------------
// RewardGNN: 2-layer GCN (256->128->64) + mean-pool + linear head.
// Round 4: parallel 3-phase scan (was: 231us single-workgroup scan).
//   - gather: 8-deep MLP unroll, scalar edge metadata
//   - gemm: LDS x-tile + 4x4 register blocking
//   - pool+head fused, no atomics
// ---------------------------------------------------------------------------

static inline int ceil_div_ll(long long a, int b) { return (int)((a + b - 1) / b); }

// deg[i]=1.0f, count[i]=0
__global__ void k_init(float* __restrict__ deg, int* __restrict__ count, int n) {
    int i = blockIdx.x * blockDim.x + threadIdx.x;
    if (i < n) { deg[i] = 1.0f; count[i] = 0; }
}

// deg[dst] += ew; count[dst] += 1
__global__ void k_deg_count(const int* __restrict__ dst, const float* __restrict__ ew,
                            float* __restrict__ deg, int* __restrict__ count, int E) {
    int e = blockIdx.x * blockDim.x + threadIdx.x;
    if (e < E) {
        int d = dst[e];
        atomicAdd(&deg[d], ew[e]);
        atomicAdd(&count[d], 1);
    }
}

__global__ void k_rsqrt(float* __restrict__ d, int n) {
    int i = blockIdx.x * blockDim.x + threadIdx.x;
    if (i < n) {
        float v = d[i];
        d[i] = (v > 0.f) ? rsqrtf(v) : 0.f;
    }
}

// ------------------------- 3-phase parallel scan ---------------------------
constexpr int SC_T = 256;                   // threads per scan block
constexpr int SC_PER = 16;                  // elements per thread
constexpr int SC_CHUNK = SC_T * SC_PER;     // 4096 elements per block

// A: blocksum[b] = sum of chunk b
__global__ void k_scan_a(const int* __restrict__ count, int* __restrict__ bsum, int n) {
    __shared__ int lds[SC_T];
    int b = blockIdx.x, t = threadIdx.x;
    int base = b * SC_CHUNK + t * SC_PER;
    int s = 0;
#pragma unroll
    for (int k = 0; k < SC_PER; ++k) {
        int idx = base + k;
        if (idx < n) s += count[idx];
    }
    lds[t] = s;
    __syncthreads();
    for (int off = 128; off > 0; off >>= 1) {
        if (t < off) lds[t] += lds[t + off];
        __syncthreads();
    }
    if (t == 0) bsum[b] = lds[0];
}

// B: exclusive scan of blocksums in place (nb ~ 25, trivial)
__global__ void k_scan_b(int* __restrict__ bsum, int nb) {
    if (threadIdx.x == 0) {
        int run = 0;
        for (int i = 0; i < nb; ++i) { int c = bsum[i]; bsum[i] = run; run += c; }
    }
}

// C: full exclusive prefix -> rowptr[0..n]; count[i] = prefix (cursor init)
__global__ void k_scan_c(int* __restrict__ count, int* __restrict__ rowptr,
                         const int* __restrict__ bsum, int n) {
    __shared__ int lds[SC_T];
    int b = blockIdx.x, t = threadIdx.x;
    int base = b * SC_CHUNK + t * SC_PER;
    int v[SC_PER];
    int s = 0;
#pragma unroll
    for (int k = 0; k < SC_PER; ++k) {
        int idx = base + k;
        v[k] = (idx < n) ? count[idx] : 0;
        s += v[k];
    }
    lds[t] = s;
    for (int off = 1; off < SC_T; off <<= 1) {
        __syncthreads();
        int tmp = (t >= off) ? lds[t - off] : 0;
        __syncthreads();
        lds[t] += tmp;
    }
    __syncthreads();
    int run = bsum[b] + lds[t] - s;   // exclusive base for this thread's span
#pragma unroll
    for (int k = 0; k < SC_PER; ++k) {
        int idx = base + k;
        if (idx < n) {
            rowptr[idx] = run;
            count[idx]  = run;
            run += v[k];
            if (idx == n - 1) rowptr[n] = run;
        }
    }
}

// Fill CSR: per edge, append (src, coef) at cursor[dst]++
__global__ void k_csr_fill(const int* __restrict__ src, const int* __restrict__ dst,
                           const float* __restrict__ ew, const float* __restrict__ dinv,
                           int* __restrict__ cursor, int* __restrict__ csr_src,
                           float* __restrict__ csr_coef, int E) {
    int e = blockIdx.x * blockDim.x + threadIdx.x;
    if (e < E) {
        int s = src[e], d = dst[e];
        int pos = atomicAdd(&cursor[d], 1);
        csr_src[pos]  = s;
        csr_coef[pos] = dinv[s] * ew[e] * dinv[d];
    }
}

// ---------------------------------------------------------------------------
// GEMM: Y[n,ODIM] = X[n,KDIM] @ W[KDIM,ODIM]
// 256 threads; x-tile staged in padded LDS; each thread computes 4 rows x 4 cols.
// ---------------------------------------------------------------------------
template <int KDIM, int ODIM>
__global__ void k_gemm(const float* __restrict__ X, const float* __restrict__ W,
                       float* __restrict__ Y, int n) {
    constexpr int JT   = ODIM / 4;
    constexpr int RY   = 256 / JT;
    constexpr int TM   = RY * 4;
    constexpr int LSTR = KDIM + 4;
    __shared__ float xs[TM * LSTR];

    int tid = threadIdx.x;
    int rowbase = blockIdx.x * TM;

    for (int idx = tid; idx < TM * (KDIM / 4); idx += 256) {
        int r = idx / (KDIM / 4), c4 = idx % (KDIM / 4);
        int row = rowbase + r;
        float4 v = (row < n) ? *(const float4*)(X + (size_t)row * KDIM + c4 * 4)
                             : make_float4(0.f, 0.f, 0.f, 0.f);
        *(float4*)(xs + r * LSTR + c4 * 4) = v;
    }
    __syncthreads();

    int jt = tid % JT, ry = tid / JT;
    int j0 = jt * 4;
    int r0 = ry * 4;

    float4 acc[4];
#pragma unroll
    for (int r = 0; r < 4; ++r) acc[r] = make_float4(0.f, 0.f, 0.f, 0.f);

    for (int k4 = 0; k4 < KDIM / 4; ++k4) {
        const float* wb = W + (size_t)(k4 * 4) * ODIM + j0;
        float4 w0 = *(const float4*)(wb + 0 * ODIM);
        float4 w1 = *(const float4*)(wb + 1 * ODIM);
        float4 w2 = *(const float4*)(wb + 2 * ODIM);
        float4 w3 = *(const float4*)(wb + 3 * ODIM);
#pragma unroll
        for (int r = 0; r < 4; ++r) {
            float4 xv = *(const float4*)(xs + (r0 + r) * LSTR + k4 * 4);
            acc[r].x += xv.x * w0.x + xv.y * w1.x + xv.z * w2.x + xv.w * w3.x;
            acc[r].y += xv.x * w0.y + xv.y * w1.y + xv.z * w2.y + xv.w * w3.y;
            acc[r].z += xv.x * w0.z + xv.y * w1.z + xv.z * w2.z + xv.w * w3.z;
            acc[r].w += xv.x * w0.w + xv.y * w1.w + xv.z * w2.w + xv.w * w3.w;
        }
    }

#pragma unroll
    for (int r = 0; r < 4; ++r) {
        int row = rowbase + r0 + r;
        if (row < n) *(float4*)(Y + (size_t)row * ODIM + j0) = acc[r];
    }
}

// ---------------------------------------------------------------------------
// Gather: out[i] = relu( dinv[i]^2 * xw[i] + sum_e coef_e * xw[src_e] + bias )
// One wave per node. 8-deep unroll for memory-level parallelism.
// ---------------------------------------------------------------------------
template <int F>
__global__ void k_gather(const float* __restrict__ xw, const int* __restrict__ rowptr,
                         const int* __restrict__ csr_src, const float* __restrict__ csr_coef,
                         const float* __restrict__ dinv, const float* __restrict__ bias,
                         float* __restrict__ out, int n) {
    int wave = threadIdx.x >> 6;
    int lane = threadIdx.x & 63;
    int i = blockIdx.x * 4 + wave;
    if (i >= n) return;

    float dv = dinv[i];
    float sl = dv * dv;
    int e0 = __builtin_amdgcn_readfirstlane(rowptr[i]);
    int e1 = __builtin_amdgcn_readfirstlane(rowptr[i + 1]);

    if constexpr (F == 128) {
        const float2* base = (const float2*)xw;
        float2 a0 = base[(size_t)i * 64 + lane];
        a0.x *= sl; a0.y *= sl;
        float2 a1 = make_float2(0.f, 0.f);
        float2 a2 = make_float2(0.f, 0.f);
        float2 a3 = make_float2(0.f, 0.f);
        int e = e0;
        for (; e + 8 <= e1; e += 8) {
            int s0 = csr_src[e + 0], s1 = csr_src[e + 1], s2 = csr_src[e + 2], s3 = csr_src[e + 3];
            int s4 = csr_src[e + 4], s5 = csr_src[e + 5], s6 = csr_src[e + 6], s7 = csr_src[e + 7];
            float c0 = csr_coef[e + 0], c1 = csr_coef[e + 1], c2 = csr_coef[e + 2], c3 = csr_coef[e + 3];
            float c4 = csr_coef[e + 4], c5 = csr_coef[e + 5], c6 = csr_coef[e + 6], c7 = csr_coef[e + 7];
            float2 v0 = base[(size_t)s0 * 64 + lane];
            float2 v1 = base[(size_t)s1 * 64 + lane];
            float2 v2 = base[(size_t)s2 * 64 + lane];
            float2 v3 = base[(size_t)s3 * 64 + lane];
            float2 v4 = base[(size_t)s4 * 64 + lane];
            float2 v5 = base[(size_t)s5 * 64 + lane];
            float2 v6 = base[(size_t)s6 * 64 + lane];
            float2 v7 = base[(size_t)s7 * 64 + lane];
            a0.x += c0 * v0.x; a0.y += c0 * v0.y;
            a1.x += c1 * v1.x; a1.y += c1 * v1.y;
            a2.x += c2 * v2.x; a2.y += c2 * v2.y;
            a3.x += c3 * v3.x; a3.y += c3 * v3.y;
            a0.x += c4 * v4.x; a0.y += c4 * v4.y;
            a1.x += c5 * v5.x; a1.y += c5 * v5.y;
            a2.x += c6 * v6.x; a2.y += c6 * v6.y;
            a3.x += c7 * v7.x; a3.y += c7 * v7.y;
        }
        for (; e + 2 <= e1; e += 2) {
            int s0 = csr_src[e + 0], s1 = csr_src[e + 1];
            float c0 = csr_coef[e + 0], c1 = csr_coef[e + 1];
            float2 v0 = base[(size_t)s0 * 64 + lane];
            float2 v1 = base[(size_t)s1 * 64 + lane];
            a0.x += c0 * v0.x; a0.y += c0 * v0.y;
            a1.x += c1 * v1.x; a1.y += c1 * v1.y;
        }
        if (e < e1) {
            int s0 = csr_src[e];
            float c0 = csr_coef[e];
            float2 v0 = base[(size_t)s0 * 64 + lane];
            a0.x += c0 * v0.x; a0.y += c0 * v0.y;
        }
        float2 bb = *((const float2*)bias + lane);
        float rx = fmaxf((a0.x + a1.x) + (a2.x + a3.x) + bb.x, 0.f);
        float ry = fmaxf((a0.y + a1.y) + (a2.y + a3.y) + bb.y, 0.f);
        float2 res = make_float2(rx, ry);
        *((float2*)(out + (size_t)i * F) + lane) = res;
    } else {  // F == 64
        float a0 = xw[(size_t)i * 64 + lane] * sl;
        float a1 = 0.f, a2 = 0.f, a3 = 0.f;
        int e = e0;
        for (; e + 8 <= e1; e += 8) {
            int s0 = csr_src[e + 0], s1 = csr_src[e + 1], s2 = csr_src[e + 2], s3 = csr_src[e + 3];
            int s4 = csr_src[e + 4], s5 = csr_src[e + 5], s6 = csr_src[e + 6], s7 = csr_src[e + 7];
            float c0 = csr_coef[e + 0], c1 = csr_coef[e + 1], c2 = csr_coef[e + 2], c3 = csr_coef[e + 3];
            float c4 = csr_coef[e + 4], c5 = csr_coef[e + 5], c6 = csr_coef[e + 6], c7 = csr_coef[e + 7];
            float v0 = xw[(size_t)s0 * 64 + lane];
            float v1 = xw[(size_t)s1 * 64 + lane];
            float v2 = xw[(size_t)s2 * 64 + lane];
            float v3 = xw[(size_t)s3 * 64 + lane];
            float v4 = xw[(size_t)s4 * 64 + lane];
            float v5 = xw[(size_t)s5 * 64 + lane];
            float v6 = xw[(size_t)s6 * 64 + lane];
            float v7 = xw[(size_t)s7 * 64 + lane];
            a0 += c0 * v0; a1 += c1 * v1; a2 += c2 * v2; a3 += c3 * v3;
            a0 += c4 * v4; a1 += c5 * v5; a2 += c6 * v6; a3 += c7 * v7;
        }
        for (; e + 2 <= e1; e += 2) {
            int s0 = csr_src[e + 0], s1 = csr_src[e + 1];
            float c0 = csr_coef[e + 0], c1 = csr_coef[e + 1];
            a0 += c0 * xw[(size_t)s0 * 64 + lane];
            a1 += c1 * xw[(size_t)s1 * 64 + lane];
        }
        if (e < e1) {
            a0 += csr_coef[e] * xw[(size_t)csr_src[e] * 64 + lane];
        }
        float res = fmaxf((a0 + a1) + (a2 + a3) + bias[lane], 0.f);
        out[(size_t)i * 64 + lane] = res;
    }
}

// ---------------------------------------------------------------------------
// Fused mean-pool + head: one block per graph (batch is sorted).
// ---------------------------------------------------------------------------
__global__ void k_pool_head(const float* __restrict__ h2, const int* __restrict__ batch,
                            const float* __restrict__ Wfc, const float* __restrict__ bfc,
                            float* __restrict__ out, int n) {
    int g = blockIdx.x;
    __shared__ int bounds[2];
    __shared__ float part[256];
    int t = threadIdx.x;
    if (t < 2) {
        int target = g + t;
        int lo = 0, hi = n;
        while (lo < hi) {
            int mid = (lo + hi) >> 1;
            if (batch[mid] < target) lo = mid + 1; else hi = mid;
        }
        bounds[t] = lo;
    }
    __syncthreads();
    int lo = bounds[0], hi = bounds[1];
    int f = t & 63, rg = t >> 6;
    float acc = 0.f;
    for (int r = lo + rg; r < hi; r += 4) acc += h2[(size_t)r * 64 + f];
    part[t] = acc;
    __syncthreads();
    if (t < 64) {
        float s = part[t] + part[t + 64] + part[t + 128] + part[t + 192];
        float cntf = (float)(hi - lo);
        float v = (s / fmaxf(cntf, 1.0f)) * Wfc[f];
#pragma unroll
        for (int o = 32; o > 0; o >>= 1) v += __shfl_down(v, o);
        if (t == 0) out[g] = v + bfc[0];
    }
}

extern "C" void kernel_launch(void* const* d_in, const int* in_sizes, int n_in,
                              void* d_out, int out_size, void* d_ws, size_t ws_size,
                              hipStream_t stream) {
    const float* x    = (const float*)d_in[0];
    const int*   ei   = (const int*)d_in[1];
    const float* ew   = (const float*)d_in[2];
    const int*   bat  = (const int*)d_in[3];
    const float* W1   = (const float*)d_in[4];
    const float* b1   = (const float*)d_in[5];
    const float* W2   = (const float*)d_in[6];
    const float* b2   = (const float*)d_in[7];
    const float* Wfc  = (const float*)d_in[8];
    const float* bfc  = (const float*)d_in[9];
    float*       out  = (float*)d_out;

    const int N = in_sizes[0] / 256;
    const int E = in_sizes[2];
    const int G = out_size;

    const int* src = ei;
    const int* dst = ei + E;

    const int NB_SCAN = (N + SC_CHUNK - 1) / SC_CHUNK;

    // workspace layout
    const int Npad = (N + 4) & ~3;
    float* deg      = (float*)d_ws;                 // N (-> dinv in place)
    int*   count    = (int*)(deg + Npad);           // N (-> cursor after scan)
    int*   rowptr   = count + Npad;                 // N+1
    int*   bsum     = rowptr + Npad;                // NB_SCAN (block sums)
    int*   csr_src  = bsum + ((NB_SCAN + 4) & ~3);  // E
    float* csr_coef = (float*)(csr_src + E);        // E
    float* bufA     = csr_coef + E;                 // N*128 : xw1, later xw2
    float* bufB     = bufA + (size_t)N * 128;       // N*128 : h1, later h2

    const int B = 256;

    // 1) degree + in-degree count
    k_init<<<ceil_div_ll(N, B), B, 0, stream>>>(deg, count, N);
    k_deg_count<<<ceil_div_ll(E, B), B, 0, stream>>>(dst, ew, deg, count, E);
    k_rsqrt<<<ceil_div_ll(N, B), B, 0, stream>>>(deg, N);

    // 2) CSR build: parallel scan + counting-sort fill
    k_scan_a<<<NB_SCAN, SC_T, 0, stream>>>(count, bsum, N);
    k_scan_b<<<1, 64, 0, stream>>>(bsum, NB_SCAN);
    k_scan_c<<<NB_SCAN, SC_T, 0, stream>>>(count, rowptr, bsum, N);
    k_csr_fill<<<ceil_div_ll(E, B), B, 0, stream>>>(src, dst, ew, deg, count,
                                                    csr_src, csr_coef, E);

    // 3) layer 1
    k_gemm<256, 128><<<ceil_div_ll(N, 32), 256, 0, stream>>>(x, W1, bufA, N);
    k_gather<128><<<ceil_div_ll(N, 4), 256, 0, stream>>>(
        bufA, rowptr, csr_src, csr_coef, deg, b1, bufB, N);

    // 4) layer 2
    k_gemm<128, 64><<<ceil_div_ll(N, 64), 256, 0, stream>>>(bufB, W2, bufA, N);
    k_gather<64><<<ceil_div_ll(N, 4), 256, 0, stream>>>(
        bufA, rowptr, csr_src, csr_coef, deg, b2, bufB, N);

    // 5) fused mean-pool + head
    k_pool_head<<<G, 256, 0, stream>>>(bufB, bat, Wfc, bfc, out, N);
}

// Round 5
// 650.911 us; speedup vs baseline: 8.0868x; 1.1905x over previous
//
#include <hip/hip_runtime.h>
#include <hip/hip_bf16.h>

// ---------------------------------------------------------------------------
// RewardGNN: 2-layer GCN (256->128->64) + mean-pool + linear head.
// Round 5: dense GEMMs via bf16 split-precision MFMA (x = hi + lo):
//   x@W ~= xh@Wh + xl@Wh + xh@Wl  (error ~2^-16 rel, MFMA f32 accum)
//   - W pre-packed into MFMA fragment layout (hi/lo) once per call
//   - A fragments loaded straight from global, converted in-register (no LDS)
// Everything else (CSR gather, scan, fused pool) unchanged.
// ---------------------------------------------------------------------------

static inline int ceil_div_ll(long long a, int b) { return (int)((a + b - 1) / b); }

typedef __attribute__((ext_vector_type(8))) short bf16x8;
typedef __attribute__((ext_vector_type(4))) float f32x4;

__device__ inline unsigned short f2bf(float f) {
    __hip_bfloat16 h = __float2bfloat16(f);  // round-to-nearest-even
    return *reinterpret_cast<unsigned short*>(&h);
}
__device__ inline float bf2f(unsigned short u) {
    unsigned int x = ((unsigned int)u) << 16;
    return __uint_as_float(x);
}

// deg[i]=1.0f, count[i]=0
__global__ void k_init(float* __restrict__ deg, int* __restrict__ count, int n) {
    int i = blockIdx.x * blockDim.x + threadIdx.x;
    if (i < n) { deg[i] = 1.0f; count[i] = 0; }
}

__global__ void k_deg_count(const int* __restrict__ dst, const float* __restrict__ ew,
                            float* __restrict__ deg, int* __restrict__ count, int E) {
    int e = blockIdx.x * blockDim.x + threadIdx.x;
    if (e < E) {
        int d = dst[e];
        atomicAdd(&deg[d], ew[e]);
        atomicAdd(&count[d], 1);
    }
}

__global__ void k_rsqrt(float* __restrict__ d, int n) {
    int i = blockIdx.x * blockDim.x + threadIdx.x;
    if (i < n) {
        float v = d[i];
        d[i] = (v > 0.f) ? rsqrtf(v) : 0.f;
    }
}

// ------------------------- 3-phase parallel scan ---------------------------
constexpr int SC_T = 256;
constexpr int SC_PER = 16;
constexpr int SC_CHUNK = SC_T * SC_PER;

__global__ void k_scan_a(const int* __restrict__ count, int* __restrict__ bsum, int n) {
    __shared__ int lds[SC_T];
    int b = blockIdx.x, t = threadIdx.x;
    int base = b * SC_CHUNK + t * SC_PER;
    int s = 0;
#pragma unroll
    for (int k = 0; k < SC_PER; ++k) {
        int idx = base + k;
        if (idx < n) s += count[idx];
    }
    lds[t] = s;
    __syncthreads();
    for (int off = 128; off > 0; off >>= 1) {
        if (t < off) lds[t] += lds[t + off];
        __syncthreads();
    }
    if (t == 0) bsum[b] = lds[0];
}

__global__ void k_scan_b(int* __restrict__ bsum, int nb) {
    if (threadIdx.x == 0) {
        int run = 0;
        for (int i = 0; i < nb; ++i) { int c = bsum[i]; bsum[i] = run; run += c; }
    }
}

__global__ void k_scan_c(int* __restrict__ count, int* __restrict__ rowptr,
                         const int* __restrict__ bsum, int n) {
    __shared__ int lds[SC_T];
    int b = blockIdx.x, t = threadIdx.x;
    int base = b * SC_CHUNK + t * SC_PER;
    int v[SC_PER];
    int s = 0;
#pragma unroll
    for (int k = 0; k < SC_PER; ++k) {
        int idx = base + k;
        v[k] = (idx < n) ? count[idx] : 0;
        s += v[k];
    }
    lds[t] = s;
    for (int off = 1; off < SC_T; off <<= 1) {
        __syncthreads();
        int tmp = (t >= off) ? lds[t - off] : 0;
        __syncthreads();
        lds[t] += tmp;
    }
    __syncthreads();
    int run = bsum[b] + lds[t] - s;
#pragma unroll
    for (int k = 0; k < SC_PER; ++k) {
        int idx = base + k;
        if (idx < n) {
            rowptr[idx] = run;
            count[idx]  = run;
            run += v[k];
            if (idx == n - 1) rowptr[n] = run;
        }
    }
}

__global__ void k_csr_fill(const int* __restrict__ src, const int* __restrict__ dst,
                           const float* __restrict__ ew, const float* __restrict__ dinv,
                           int* __restrict__ cursor, int* __restrict__ csr_src,
                           float* __restrict__ csr_coef, int E) {
    int e = blockIdx.x * blockDim.x + threadIdx.x;
    if (e < E) {
        int s = src[e], d = dst[e];
        int pos = atomicAdd(&cursor[d], 1);
        csr_src[pos]  = s;
        csr_coef[pos] = dinv[s] * ew[e] * dinv[d];
    }
}

// ---------------------------------------------------------------------------
// W pre-pack into MFMA B-fragment layout (hi/lo bf16).
// Fragment (ks, nf, lane) holds W[ks*32 + (lane>>4)*8 + i][nf*16 + (lane&15)],
// i = 0..7.  wpk = [hi: KDIM*ODIM elems][lo: KDIM*ODIM elems].
// ---------------------------------------------------------------------------
template <int KDIM, int ODIM>
__global__ void k_wpack(const float* __restrict__ W, unsigned short* __restrict__ wpk) {
    constexpr int NKS = KDIM / 32, NF = ODIM / 16;
    int t = blockIdx.x * blockDim.x + threadIdx.x;
    if (t >= NKS * NF * 64) return;
    int lane = t & 63;
    int nf   = (t >> 6) % NF;
    int ks   = t / (64 * NF);
    int col  = nf * 16 + (lane & 15);
    int kb   = ks * 32 + (lane >> 4) * 8;
    bf16x8 hi, lo;
#pragma unroll
    for (int i = 0; i < 8; ++i) {
        float w = W[(size_t)(kb + i) * ODIM + col];
        unsigned short h = f2bf(w);
        hi[i] = (short)h;
        lo[i] = (short)f2bf(w - bf2f(h));
    }
    size_t base = (size_t)t * 8;  // t == (ks*NF + nf)*64 + lane
    *(bf16x8*)(wpk + base) = hi;
    *(bf16x8*)(wpk + (size_t)KDIM * ODIM + base) = lo;
}

// ---------------------------------------------------------------------------
// GEMM via mfma_f32_16x16x32_bf16, split-precision.
// Block = 4 waves; wave w computes rows [blk*64 + w*16, +16) x ODIM.
// A loaded from global per wave (no reuse across waves), converted in-reg.
// ---------------------------------------------------------------------------
template <int KDIM, int ODIM>
__global__ void k_gemm_mfma(const float* __restrict__ X,
                            const unsigned short* __restrict__ wpk,
                            float* __restrict__ Y, int n) {
    constexpr int NKS = KDIM / 32, NF = ODIM / 16;
    int wid  = threadIdx.x >> 6;
    int lane = threadIdx.x & 63;
    int rowbase = blockIdx.x * 64 + wid * 16;
    int arow = rowbase + (lane & 15);
    int kb0  = (lane >> 4) * 8;
    const unsigned short* wlo = wpk + (size_t)KDIM * ODIM;
    bool aok = (arow < n);
    const float* xr = X + (size_t)arow * KDIM + kb0;

    f32x4 acc[NF];
#pragma unroll
    for (int f = 0; f < NF; ++f) acc[f] = (f32x4){0.f, 0.f, 0.f, 0.f};

#pragma unroll
    for (int ks = 0; ks < NKS; ++ks) {
        f32x4 a0 = (f32x4){0.f, 0.f, 0.f, 0.f};
        f32x4 a1 = (f32x4){0.f, 0.f, 0.f, 0.f};
        if (aok) {
            a0 = *(const f32x4*)(xr + ks * 32);
            a1 = *(const f32x4*)(xr + ks * 32 + 4);
        }
        bf16x8 ahi, alo;
#pragma unroll
        for (int i = 0; i < 4; ++i) {
            unsigned short h0 = f2bf(a0[i]);
            ahi[i]     = (short)h0;
            alo[i]     = (short)f2bf(a0[i] - bf2f(h0));
            unsigned short h1 = f2bf(a1[i]);
            ahi[i + 4] = (short)h1;
            alo[i + 4] = (short)f2bf(a1[i] - bf2f(h1));
        }
#pragma unroll
        for (int f = 0; f < NF; ++f) {
            size_t fb = (((size_t)ks * NF + f) * 64 + lane) * 8;
            bf16x8 bhi = *(const bf16x8*)(wpk + fb);
            bf16x8 blo = *(const bf16x8*)(wlo + fb);
            acc[f] = __builtin_amdgcn_mfma_f32_16x16x32_bf16(ahi, bhi, acc[f], 0, 0, 0);
            acc[f] = __builtin_amdgcn_mfma_f32_16x16x32_bf16(alo, bhi, acc[f], 0, 0, 0);
            acc[f] = __builtin_amdgcn_mfma_f32_16x16x32_bf16(ahi, blo, acc[f], 0, 0, 0);
        }
    }

    int r0  = rowbase + (lane >> 4) * 4;
    int col = lane & 15;
#pragma unroll
    for (int f = 0; f < NF; ++f) {
#pragma unroll
        for (int i = 0; i < 4; ++i) {
            int r = r0 + i;
            if (r < n) Y[(size_t)r * ODIM + f * 16 + col] = acc[f][i];
        }
    }
}

// ---------------------------------------------------------------------------
// Gather: out[i] = relu( dinv[i]^2 * xw[i] + sum_e coef_e * xw[src_e] + bias )
// One wave per node. 8-deep unroll for memory-level parallelism.
// ---------------------------------------------------------------------------
template <int F>
__global__ void k_gather(const float* __restrict__ xw, const int* __restrict__ rowptr,
                         const int* __restrict__ csr_src, const float* __restrict__ csr_coef,
                         const float* __restrict__ dinv, const float* __restrict__ bias,
                         float* __restrict__ out, int n) {
    int wave = threadIdx.x >> 6;
    int lane = threadIdx.x & 63;
    int i = blockIdx.x * 4 + wave;
    if (i >= n) return;

    float dv = dinv[i];
    float sl = dv * dv;
    int e0 = __builtin_amdgcn_readfirstlane(rowptr[i]);
    int e1 = __builtin_amdgcn_readfirstlane(rowptr[i + 1]);

    if constexpr (F == 128) {
        const float2* base = (const float2*)xw;
        float2 a0 = base[(size_t)i * 64 + lane];
        a0.x *= sl; a0.y *= sl;
        float2 a1 = make_float2(0.f, 0.f);
        float2 a2 = make_float2(0.f, 0.f);
        float2 a3 = make_float2(0.f, 0.f);
        int e = e0;
        for (; e + 8 <= e1; e += 8) {
            int s0 = csr_src[e + 0], s1 = csr_src[e + 1], s2 = csr_src[e + 2], s3 = csr_src[e + 3];
            int s4 = csr_src[e + 4], s5 = csr_src[e + 5], s6 = csr_src[e + 6], s7 = csr_src[e + 7];
            float c0 = csr_coef[e + 0], c1 = csr_coef[e + 1], c2 = csr_coef[e + 2], c3 = csr_coef[e + 3];
            float c4 = csr_coef[e + 4], c5 = csr_coef[e + 5], c6 = csr_coef[e + 6], c7 = csr_coef[e + 7];
            float2 v0 = base[(size_t)s0 * 64 + lane];
            float2 v1 = base[(size_t)s1 * 64 + lane];
            float2 v2 = base[(size_t)s2 * 64 + lane];
            float2 v3 = base[(size_t)s3 * 64 + lane];
            float2 v4 = base[(size_t)s4 * 64 + lane];
            float2 v5 = base[(size_t)s5 * 64 + lane];
            float2 v6 = base[(size_t)s6 * 64 + lane];
            float2 v7 = base[(size_t)s7 * 64 + lane];
            a0.x += c0 * v0.x; a0.y += c0 * v0.y;
            a1.x += c1 * v1.x; a1.y += c1 * v1.y;
            a2.x += c2 * v2.x; a2.y += c2 * v2.y;
            a3.x += c3 * v3.x; a3.y += c3 * v3.y;
            a0.x += c4 * v4.x; a0.y += c4 * v4.y;
            a1.x += c5 * v5.x; a1.y += c5 * v5.y;
            a2.x += c6 * v6.x; a2.y += c6 * v6.y;
            a3.x += c7 * v7.x; a3.y += c7 * v7.y;
        }
        for (; e + 2 <= e1; e += 2) {
            int s0 = csr_src[e + 0], s1 = csr_src[e + 1];
            float c0 = csr_coef[e + 0], c1 = csr_coef[e + 1];
            float2 v0 = base[(size_t)s0 * 64 + lane];
            float2 v1 = base[(size_t)s1 * 64 + lane];
            a0.x += c0 * v0.x; a0.y += c0 * v0.y;
            a1.x += c1 * v1.x; a1.y += c1 * v1.y;
        }
        if (e < e1) {
            int s0 = csr_src[e];
            float c0 = csr_coef[e];
            float2 v0 = base[(size_t)s0 * 64 + lane];
            a0.x += c0 * v0.x; a0.y += c0 * v0.y;
        }
        float2 bb = *((const float2*)bias + lane);
        float rx = fmaxf((a0.x + a1.x) + (a2.x + a3.x) + bb.x, 0.f);
        float ry = fmaxf((a0.y + a1.y) + (a2.y + a3.y) + bb.y, 0.f);
        float2 res = make_float2(rx, ry);
        *((float2*)(out + (size_t)i * F) + lane) = res;
    } else {  // F == 64
        float a0 = xw[(size_t)i * 64 + lane] * sl;
        float a1 = 0.f, a2 = 0.f, a3 = 0.f;
        int e = e0;
        for (; e + 8 <= e1; e += 8) {
            int s0 = csr_src[e + 0], s1 = csr_src[e + 1], s2 = csr_src[e + 2], s3 = csr_src[e + 3];
            int s4 = csr_src[e + 4], s5 = csr_src[e + 5], s6 = csr_src[e + 6], s7 = csr_src[e + 7];
            float c0 = csr_coef[e + 0], c1 = csr_coef[e + 1], c2 = csr_coef[e + 2], c3 = csr_coef[e + 3];
            float c4 = csr_coef[e + 4], c5 = csr_coef[e + 5], c6 = csr_coef[e + 6], c7 = csr_coef[e + 7];
            float v0 = xw[(size_t)s0 * 64 + lane];
            float v1 = xw[(size_t)s1 * 64 + lane];
            float v2 = xw[(size_t)s2 * 64 + lane];
            float v3 = xw[(size_t)s3 * 64 + lane];
            float v4 = xw[(size_t)s4 * 64 + lane];
            float v5 = xw[(size_t)s5 * 64 + lane];
            float v6 = xw[(size_t)s6 * 64 + lane];
            float v7 = xw[(size_t)s7 * 64 + lane];
            a0 += c0 * v0; a1 += c1 * v1; a2 += c2 * v2; a3 += c3 * v3;
            a0 += c4 * v4; a1 += c5 * v5; a2 += c6 * v6; a3 += c7 * v7;
        }
        for (; e + 2 <= e1; e += 2) {
            int s0 = csr_src[e + 0], s1 = csr_src[e + 1];
            float c0 = csr_coef[e + 0], c1 = csr_coef[e + 1];
            a0 += c0 * xw[(size_t)s0 * 64 + lane];
            a1 += c1 * xw[(size_t)s1 * 64 + lane];
        }
        if (e < e1) {
            a0 += csr_coef[e] * xw[(size_t)csr_src[e] * 64 + lane];
        }
        float res = fmaxf((a0 + a1) + (a2 + a3) + bias[lane], 0.f);
        out[(size_t)i * 64 + lane] = res;
    }
}

// ---------------------------------------------------------------------------
// Fused mean-pool + head: one block per graph (batch is sorted).
// ---------------------------------------------------------------------------
__global__ void k_pool_head(const float* __restrict__ h2, const int* __restrict__ batch,
                            const float* __restrict__ Wfc, const float* __restrict__ bfc,
                            float* __restrict__ out, int n) {
    int g = blockIdx.x;
    __shared__ int bounds[2];
    __shared__ float part[256];
    int t = threadIdx.x;
    if (t < 2) {
        int target = g + t;
        int lo = 0, hi = n;
        while (lo < hi) {
            int mid = (lo + hi) >> 1;
            if (batch[mid] < target) lo = mid + 1; else hi = mid;
        }
        bounds[t] = lo;
    }
    __syncthreads();
    int lo = bounds[0], hi = bounds[1];
    int f = t & 63, rg = t >> 6;
    float acc = 0.f;
    for (int r = lo + rg; r < hi; r += 4) acc += h2[(size_t)r * 64 + f];
    part[t] = acc;
    __syncthreads();
    if (t < 64) {
        float s = part[t] + part[t + 64] + part[t + 128] + part[t + 192];
        float cntf = (float)(hi - lo);
        float v = (s / fmaxf(cntf, 1.0f)) * Wfc[f];
#pragma unroll
        for (int o = 32; o > 0; o >>= 1) v += __shfl_down(v, o);
        if (t == 0) out[g] = v + bfc[0];
    }
}

extern "C" void kernel_launch(void* const* d_in, const int* in_sizes, int n_in,
                              void* d_out, int out_size, void* d_ws, size_t ws_size,
                              hipStream_t stream) {
    const float* x    = (const float*)d_in[0];
    const int*   ei   = (const int*)d_in[1];
    const float* ew   = (const float*)d_in[2];
    const int*   bat  = (const int*)d_in[3];
    const float* W1   = (const float*)d_in[4];
    const float* b1   = (const float*)d_in[5];
    const float* W2   = (const float*)d_in[6];
    const float* b2   = (const float*)d_in[7];
    const float* Wfc  = (const float*)d_in[8];
    const float* bfc  = (const float*)d_in[9];
    float*       out  = (float*)d_out;

    const int N = in_sizes[0] / 256;
    const int E = in_sizes[2];
    const int G = out_size;

    const int* src = ei;
    const int* dst = ei + E;

    const int NB_SCAN = (N + SC_CHUNK - 1) / SC_CHUNK;

    // workspace layout (f32-unit offsets; all chunks multiple of 4 floats)
    const int Npad = (N + 4) & ~3;
    float*          deg      = (float*)d_ws;                    // N (-> dinv)
    int*            count    = (int*)(deg + Npad);               // N (-> cursor)
    int*            rowptr   = count + Npad;                     // N+1
    int*            bsum     = rowptr + Npad;                    // NB_SCAN
    int*            csr_src  = bsum + ((NB_SCAN + 4) & ~3);      // E
    float*          csr_coef = (float*)(csr_src + E);           // E
    unsigned short* wpk1     = (unsigned short*)(csr_coef + E); // 2*256*128 ushort
    unsigned short* wpk2     = wpk1 + 2 * 256 * 128;             // 2*128*64 ushort
    float*          bufA     = (float*)(wpk2 + 2 * 128 * 64);   // N*128 : xw1/xw2
    float*          bufB     = bufA + (size_t)N * 128;           // N*128 : h1/h2

    const int B = 256;

    // 1) degree + in-degree count
    k_init<<<ceil_div_ll(N, B), B, 0, stream>>>(deg, count, N);
    k_deg_count<<<ceil_div_ll(E, B), B, 0, stream>>>(dst, ew, deg, count, E);
    k_rsqrt<<<ceil_div_ll(N, B), B, 0, stream>>>(deg, N);

    // 2) CSR build: parallel scan + counting-sort fill
    k_scan_a<<<NB_SCAN, SC_T, 0, stream>>>(count, bsum, N);
    k_scan_b<<<1, 64, 0, stream>>>(bsum, NB_SCAN);
    k_scan_c<<<NB_SCAN, SC_T, 0, stream>>>(count, rowptr, bsum, N);
    k_csr_fill<<<ceil_div_ll(E, B), B, 0, stream>>>(src, dst, ew, deg, count,
                                                    csr_src, csr_coef, E);

    // W pre-pack (cheap; independent of the above)
    k_wpack<256, 128><<<(8 * 8 * 64 + B - 1) / B, B, 0, stream>>>(W1, wpk1);
    k_wpack<128, 64><<<(4 * 4 * 64 + B - 1) / B, B, 0, stream>>>(W2, wpk2);

    // 3) layer 1
    k_gemm_mfma<256, 128><<<ceil_div_ll(N, 64), 256, 0, stream>>>(x, wpk1, bufA, N);
    k_gather<128><<<ceil_div_ll(N, 4), 256, 0, stream>>>(
        bufA, rowptr, csr_src, csr_coef, deg, b1, bufB, N);

    // 4) layer 2
    k_gemm_mfma<128, 64><<<ceil_div_ll(N, 64), 256, 0, stream>>>(bufB, wpk2, bufA, N);
    k_gather<64><<<ceil_div_ll(N, 4), 256, 0, stream>>>(
        bufA, rowptr, csr_src, csr_coef, deg, b2, bufB, N);

    // 5) fused mean-pool + head
    k_pool_head<<<G, 256, 0, stream>>>(bufB, bat, Wfc, bfc, out, N);
}

// Round 6
// 595.374 us; speedup vs baseline: 8.8412x; 1.0933x over previous
//
#include <hip/hip_runtime.h>
#include <hip/hip_bf16.h>

// ---------------------------------------------------------------------------
// RewardGNN: 2-layer GCN (256->128->64) + mean-pool + linear head.
// Round 6: gathers are BW-bound on random row reads (3.8 TB/s wall) ->
//   store GEMM outputs xw1/xw2 as bf16 (halves gather read bytes).
//   GEMMs: bf16 split-precision MFMA (x = hi+lo), W pre-packed per call.
//   h1/h2 stay f32 so GEMM2 keeps a full-precision input.
// ---------------------------------------------------------------------------

static inline int ceil_div_ll(long long a, int b) { return (int)((a + b - 1) / b); }

typedef __attribute__((ext_vector_type(8))) short bf16x8;
typedef __attribute__((ext_vector_type(4))) float f32x4;

__device__ inline unsigned short f2bf(float f) {
    __hip_bfloat16 h = __float2bfloat16(f);  // round-to-nearest-even
    return *reinterpret_cast<unsigned short*>(&h);
}
__device__ inline float bf2f(unsigned short u) {
    unsigned int x = ((unsigned int)u) << 16;
    return __uint_as_float(x);
}

// deg[i]=1.0f, count[i]=0
__global__ void k_init(float* __restrict__ deg, int* __restrict__ count, int n) {
    int i = blockIdx.x * blockDim.x + threadIdx.x;
    if (i < n) { deg[i] = 1.0f; count[i] = 0; }
}

__global__ void k_deg_count(const int* __restrict__ dst, const float* __restrict__ ew,
                            float* __restrict__ deg, int* __restrict__ count, int E) {
    int e = blockIdx.x * blockDim.x + threadIdx.x;
    if (e < E) {
        int d = dst[e];
        atomicAdd(&deg[d], ew[e]);
        atomicAdd(&count[d], 1);
    }
}

__global__ void k_rsqrt(float* __restrict__ d, int n) {
    int i = blockIdx.x * blockDim.x + threadIdx.x;
    if (i < n) {
        float v = d[i];
        d[i] = (v > 0.f) ? rsqrtf(v) : 0.f;
    }
}

// ------------------------- 3-phase parallel scan ---------------------------
constexpr int SC_T = 256;
constexpr int SC_PER = 16;
constexpr int SC_CHUNK = SC_T * SC_PER;

__global__ void k_scan_a(const int* __restrict__ count, int* __restrict__ bsum, int n) {
    __shared__ int lds[SC_T];
    int b = blockIdx.x, t = threadIdx.x;
    int base = b * SC_CHUNK + t * SC_PER;
    int s = 0;
#pragma unroll
    for (int k = 0; k < SC_PER; ++k) {
        int idx = base + k;
        if (idx < n) s += count[idx];
    }
    lds[t] = s;
    __syncthreads();
    for (int off = 128; off > 0; off >>= 1) {
        if (t < off) lds[t] += lds[t + off];
        __syncthreads();
    }
    if (t == 0) bsum[b] = lds[0];
}

__global__ void k_scan_b(int* __restrict__ bsum, int nb) {
    if (threadIdx.x == 0) {
        int run = 0;
        for (int i = 0; i < nb; ++i) { int c = bsum[i]; bsum[i] = run; run += c; }
    }
}

__global__ void k_scan_c(int* __restrict__ count, int* __restrict__ rowptr,
                         const int* __restrict__ bsum, int n) {
    __shared__ int lds[SC_T];
    int b = blockIdx.x, t = threadIdx.x;
    int base = b * SC_CHUNK + t * SC_PER;
    int v[SC_PER];
    int s = 0;
#pragma unroll
    for (int k = 0; k < SC_PER; ++k) {
        int idx = base + k;
        v[k] = (idx < n) ? count[idx] : 0;
        s += v[k];
    }
    lds[t] = s;
    for (int off = 1; off < SC_T; off <<= 1) {
        __syncthreads();
        int tmp = (t >= off) ? lds[t - off] : 0;
        __syncthreads();
        lds[t] += tmp;
    }
    __syncthreads();
    int run = bsum[b] + lds[t] - s;
#pragma unroll
    for (int k = 0; k < SC_PER; ++k) {
        int idx = base + k;
        if (idx < n) {
            rowptr[idx] = run;
            count[idx]  = run;
            run += v[k];
            if (idx == n - 1) rowptr[n] = run;
        }
    }
}

__global__ void k_csr_fill(const int* __restrict__ src, const int* __restrict__ dst,
                           const float* __restrict__ ew, const float* __restrict__ dinv,
                           int* __restrict__ cursor, int* __restrict__ csr_src,
                           float* __restrict__ csr_coef, int E) {
    int e = blockIdx.x * blockDim.x + threadIdx.x;
    if (e < E) {
        int s = src[e], d = dst[e];
        int pos = atomicAdd(&cursor[d], 1);
        csr_src[pos]  = s;
        csr_coef[pos] = dinv[s] * ew[e] * dinv[d];
    }
}

// ---------------------------------------------------------------------------
// W pre-pack into MFMA B-fragment layout (hi/lo bf16).
// ---------------------------------------------------------------------------
template <int KDIM, int ODIM>
__global__ void k_wpack(const float* __restrict__ W, unsigned short* __restrict__ wpk) {
    constexpr int NKS = KDIM / 32, NF = ODIM / 16;
    int t = blockIdx.x * blockDim.x + threadIdx.x;
    if (t >= NKS * NF * 64) return;
    int lane = t & 63;
    int nf   = (t >> 6) % NF;
    int ks   = t / (64 * NF);
    int col  = nf * 16 + (lane & 15);
    int kb   = ks * 32 + (lane >> 4) * 8;
    bf16x8 hi, lo;
#pragma unroll
    for (int i = 0; i < 8; ++i) {
        float w = W[(size_t)(kb + i) * ODIM + col];
        unsigned short h = f2bf(w);
        hi[i] = (short)h;
        lo[i] = (short)f2bf(w - bf2f(h));
    }
    size_t base = (size_t)t * 8;
    *(bf16x8*)(wpk + base) = hi;
    *(bf16x8*)(wpk + (size_t)KDIM * ODIM + base) = lo;
}

// ---------------------------------------------------------------------------
// GEMM via mfma_f32_16x16x32_bf16, split-precision; OUTPUT IS bf16.
// Block = 4 waves; wave w computes rows [blk*64 + w*16, +16) x ODIM.
// ---------------------------------------------------------------------------
template <int KDIM, int ODIM>
__global__ void k_gemm_mfma(const float* __restrict__ X,
                            const unsigned short* __restrict__ wpk,
                            unsigned short* __restrict__ Y, int n) {
    constexpr int NKS = KDIM / 32, NF = ODIM / 16;
    int wid  = threadIdx.x >> 6;
    int lane = threadIdx.x & 63;
    int rowbase = blockIdx.x * 64 + wid * 16;
    int arow = rowbase + (lane & 15);
    int kb0  = (lane >> 4) * 8;
    const unsigned short* wlo = wpk + (size_t)KDIM * ODIM;
    bool aok = (arow < n);
    const float* xr = X + (size_t)arow * KDIM + kb0;

    f32x4 acc[NF];
#pragma unroll
    for (int f = 0; f < NF; ++f) acc[f] = (f32x4){0.f, 0.f, 0.f, 0.f};

#pragma unroll
    for (int ks = 0; ks < NKS; ++ks) {
        f32x4 a0 = (f32x4){0.f, 0.f, 0.f, 0.f};
        f32x4 a1 = (f32x4){0.f, 0.f, 0.f, 0.f};
        if (aok) {
            a0 = *(const f32x4*)(xr + ks * 32);
            a1 = *(const f32x4*)(xr + ks * 32 + 4);
        }
        bf16x8 ahi, alo;
#pragma unroll
        for (int i = 0; i < 4; ++i) {
            unsigned short h0 = f2bf(a0[i]);
            ahi[i]     = (short)h0;
            alo[i]     = (short)f2bf(a0[i] - bf2f(h0));
            unsigned short h1 = f2bf(a1[i]);
            ahi[i + 4] = (short)h1;
            alo[i + 4] = (short)f2bf(a1[i] - bf2f(h1));
        }
#pragma unroll
        for (int f = 0; f < NF; ++f) {
            size_t fb = (((size_t)ks * NF + f) * 64 + lane) * 8;
            bf16x8 bhi = *(const bf16x8*)(wpk + fb);
            bf16x8 blo = *(const bf16x8*)(wlo + fb);
            acc[f] = __builtin_amdgcn_mfma_f32_16x16x32_bf16(ahi, bhi, acc[f], 0, 0, 0);
            acc[f] = __builtin_amdgcn_mfma_f32_16x16x32_bf16(alo, bhi, acc[f], 0, 0, 0);
            acc[f] = __builtin_amdgcn_mfma_f32_16x16x32_bf16(ahi, blo, acc[f], 0, 0, 0);
        }
    }

    int r0  = rowbase + (lane >> 4) * 4;
    int col = lane & 15;
#pragma unroll
    for (int f = 0; f < NF; ++f) {
#pragma unroll
        for (int i = 0; i < 4; ++i) {
            int r = r0 + i;
            if (r < n) Y[(size_t)r * ODIM + f * 16 + col] = f2bf(acc[f][i]);
        }
    }
}

// ---------------------------------------------------------------------------
// Gather (bf16 input rows, f32 accumulate/output):
//   out[i] = relu( dinv[i]^2 * xw[i] + sum_e coef_e * xw[src_e] + bias )
// One wave per node; 8-deep unroll for memory-level parallelism.
// F=128: lane holds features (2*lane, 2*lane+1) via one u32 load.
// F=64 : lane holds feature lane via one u16 load.
// ---------------------------------------------------------------------------
template <int F>
__global__ void k_gather(const unsigned short* __restrict__ xw, const int* __restrict__ rowptr,
                         const int* __restrict__ csr_src, const float* __restrict__ csr_coef,
                         const float* __restrict__ dinv, const float* __restrict__ bias,
                         float* __restrict__ out, int n) {
    int wave = threadIdx.x >> 6;
    int lane = threadIdx.x & 63;
    int i = blockIdx.x * 4 + wave;
    if (i >= n) return;

    float dv = dinv[i];
    float sl = dv * dv;
    int e0 = __builtin_amdgcn_readfirstlane(rowptr[i]);
    int e1 = __builtin_amdgcn_readfirstlane(rowptr[i + 1]);

    if constexpr (F == 128) {
        const unsigned int* base = (const unsigned int*)xw;  // row stride 64 u32
        unsigned int su = base[(size_t)i * 64 + lane];
        float ax0 = bf2f((unsigned short)(su & 0xffff)) * sl;
        float ay0 = bf2f((unsigned short)(su >> 16)) * sl;
        float ax1 = 0.f, ay1 = 0.f, ax2 = 0.f, ay2 = 0.f, ax3 = 0.f, ay3 = 0.f;
        int e = e0;
        for (; e + 8 <= e1; e += 8) {
            int s0 = csr_src[e + 0], s1 = csr_src[e + 1], s2 = csr_src[e + 2], s3 = csr_src[e + 3];
            int s4 = csr_src[e + 4], s5 = csr_src[e + 5], s6 = csr_src[e + 6], s7 = csr_src[e + 7];
            float c0 = csr_coef[e + 0], c1 = csr_coef[e + 1], c2 = csr_coef[e + 2], c3 = csr_coef[e + 3];
            float c4 = csr_coef[e + 4], c5 = csr_coef[e + 5], c6 = csr_coef[e + 6], c7 = csr_coef[e + 7];
            unsigned int u0 = base[(size_t)s0 * 64 + lane];
            unsigned int u1 = base[(size_t)s1 * 64 + lane];
            unsigned int u2 = base[(size_t)s2 * 64 + lane];
            unsigned int u3 = base[(size_t)s3 * 64 + lane];
            unsigned int u4 = base[(size_t)s4 * 64 + lane];
            unsigned int u5 = base[(size_t)s5 * 64 + lane];
            unsigned int u6 = base[(size_t)s6 * 64 + lane];
            unsigned int u7 = base[(size_t)s7 * 64 + lane];
            ax0 += c0 * bf2f((unsigned short)(u0 & 0xffff)); ay0 += c0 * bf2f((unsigned short)(u0 >> 16));
            ax1 += c1 * bf2f((unsigned short)(u1 & 0xffff)); ay1 += c1 * bf2f((unsigned short)(u1 >> 16));
            ax2 += c2 * bf2f((unsigned short)(u2 & 0xffff)); ay2 += c2 * bf2f((unsigned short)(u2 >> 16));
            ax3 += c3 * bf2f((unsigned short)(u3 & 0xffff)); ay3 += c3 * bf2f((unsigned short)(u3 >> 16));
            ax0 += c4 * bf2f((unsigned short)(u4 & 0xffff)); ay0 += c4 * bf2f((unsigned short)(u4 >> 16));
            ax1 += c5 * bf2f((unsigned short)(u5 & 0xffff)); ay1 += c5 * bf2f((unsigned short)(u5 >> 16));
            ax2 += c6 * bf2f((unsigned short)(u6 & 0xffff)); ay2 += c6 * bf2f((unsigned short)(u6 >> 16));
            ax3 += c7 * bf2f((unsigned short)(u7 & 0xffff)); ay3 += c7 * bf2f((unsigned short)(u7 >> 16));
        }
        for (; e + 2 <= e1; e += 2) {
            int s0 = csr_src[e + 0], s1 = csr_src[e + 1];
            float c0 = csr_coef[e + 0], c1 = csr_coef[e + 1];
            unsigned int u0 = base[(size_t)s0 * 64 + lane];
            unsigned int u1 = base[(size_t)s1 * 64 + lane];
            ax0 += c0 * bf2f((unsigned short)(u0 & 0xffff)); ay0 += c0 * bf2f((unsigned short)(u0 >> 16));
            ax1 += c1 * bf2f((unsigned short)(u1 & 0xffff)); ay1 += c1 * bf2f((unsigned short)(u1 >> 16));
        }
        if (e < e1) {
            int s0 = csr_src[e];
            float c0 = csr_coef[e];
            unsigned int u0 = base[(size_t)s0 * 64 + lane];
            ax0 += c0 * bf2f((unsigned short)(u0 & 0xffff)); ay0 += c0 * bf2f((unsigned short)(u0 >> 16));
        }
        float2 bb = *((const float2*)bias + lane);
        float rx = fmaxf((ax0 + ax1) + (ax2 + ax3) + bb.x, 0.f);
        float ry = fmaxf((ay0 + ay1) + (ay2 + ay3) + bb.y, 0.f);
        *((float2*)(out + (size_t)i * F) + lane) = make_float2(rx, ry);
    } else {  // F == 64
        float a0 = bf2f(xw[(size_t)i * 64 + lane]) * sl;
        float a1 = 0.f, a2 = 0.f, a3 = 0.f;
        int e = e0;
        for (; e + 8 <= e1; e += 8) {
            int s0 = csr_src[e + 0], s1 = csr_src[e + 1], s2 = csr_src[e + 2], s3 = csr_src[e + 3];
            int s4 = csr_src[e + 4], s5 = csr_src[e + 5], s6 = csr_src[e + 6], s7 = csr_src[e + 7];
            float c0 = csr_coef[e + 0], c1 = csr_coef[e + 1], c2 = csr_coef[e + 2], c3 = csr_coef[e + 3];
            float c4 = csr_coef[e + 4], c5 = csr_coef[e + 5], c6 = csr_coef[e + 6], c7 = csr_coef[e + 7];
            float v0 = bf2f(xw[(size_t)s0 * 64 + lane]);
            float v1 = bf2f(xw[(size_t)s1 * 64 + lane]);
            float v2 = bf2f(xw[(size_t)s2 * 64 + lane]);
            float v3 = bf2f(xw[(size_t)s3 * 64 + lane]);
            float v4 = bf2f(xw[(size_t)s4 * 64 + lane]);
            float v5 = bf2f(xw[(size_t)s5 * 64 + lane]);
            float v6 = bf2f(xw[(size_t)s6 * 64 + lane]);
            float v7 = bf2f(xw[(size_t)s7 * 64 + lane]);
            a0 += c0 * v0; a1 += c1 * v1; a2 += c2 * v2; a3 += c3 * v3;
            a0 += c4 * v4; a1 += c5 * v5; a2 += c6 * v6; a3 += c7 * v7;
        }
        for (; e + 2 <= e1; e += 2) {
            int s0 = csr_src[e + 0], s1 = csr_src[e + 1];
            float c0 = csr_coef[e + 0], c1 = csr_coef[e + 1];
            a0 += c0 * bf2f(xw[(size_t)s0 * 64 + lane]);
            a1 += c1 * bf2f(xw[(size_t)s1 * 64 + lane]);
        }
        if (e < e1) {
            a0 += csr_coef[e] * bf2f(xw[(size_t)csr_src[e] * 64 + lane]);
        }
        float res = fmaxf((a0 + a1) + (a2 + a3) + bias[lane], 0.f);
        out[(size_t)i * 64 + lane] = res;
    }
}

// ---------------------------------------------------------------------------
// Fused mean-pool + head: one block per graph (batch is sorted).
// ---------------------------------------------------------------------------
__global__ void k_pool_head(const float* __restrict__ h2, const int* __restrict__ batch,
                            const float* __restrict__ Wfc, const float* __restrict__ bfc,
                            float* __restrict__ out, int n) {
    int g = blockIdx.x;
    __shared__ int bounds[2];
    __shared__ float part[256];
    int t = threadIdx.x;
    if (t < 2) {
        int target = g + t;
        int lo = 0, hi = n;
        while (lo < hi) {
            int mid = (lo + hi) >> 1;
            if (batch[mid] < target) lo = mid + 1; else hi = mid;
        }
        bounds[t] = lo;
    }
    __syncthreads();
    int lo = bounds[0], hi = bounds[1];
    int f = t & 63, rg = t >> 6;
    float acc = 0.f;
    for (int r = lo + rg; r < hi; r += 4) acc += h2[(size_t)r * 64 + f];
    part[t] = acc;
    __syncthreads();
    if (t < 64) {
        float s = part[t] + part[t + 64] + part[t + 128] + part[t + 192];
        float cntf = (float)(hi - lo);
        float v = (s / fmaxf(cntf, 1.0f)) * Wfc[f];
#pragma unroll
        for (int o = 32; o > 0; o >>= 1) v += __shfl_down(v, o);
        if (t == 0) out[g] = v + bfc[0];
    }
}

extern "C" void kernel_launch(void* const* d_in, const int* in_sizes, int n_in,
                              void* d_out, int out_size, void* d_ws, size_t ws_size,
                              hipStream_t stream) {
    const float* x    = (const float*)d_in[0];
    const int*   ei   = (const int*)d_in[1];
    const float* ew   = (const float*)d_in[2];
    const int*   bat  = (const int*)d_in[3];
    const float* W1   = (const float*)d_in[4];
    const float* b1   = (const float*)d_in[5];
    const float* W2   = (const float*)d_in[6];
    const float* b2   = (const float*)d_in[7];
    const float* Wfc  = (const float*)d_in[8];
    const float* bfc  = (const float*)d_in[9];
    float*       out  = (float*)d_out;

    const int N = in_sizes[0] / 256;
    const int E = in_sizes[2];
    const int G = out_size;

    const int* src = ei;
    const int* dst = ei + E;

    const int NB_SCAN = (N + SC_CHUNK - 1) / SC_CHUNK;

    // workspace layout (f32-unit offsets; all chunks multiple of 4 floats)
    const int Npad = (N + 4) & ~3;
    float*          deg      = (float*)d_ws;                    // N (-> dinv)
    int*            count    = (int*)(deg + Npad);               // N (-> cursor)
    int*            rowptr   = count + Npad;                     // N+1
    int*            bsum     = rowptr + Npad;                    // NB_SCAN
    int*            csr_src  = bsum + ((NB_SCAN + 4) & ~3);      // E
    float*          csr_coef = (float*)(csr_src + E);           // E
    unsigned short* wpk1     = (unsigned short*)(csr_coef + E); // 2*256*128 ushort
    unsigned short* wpk2     = wpk1 + 2 * 256 * 128;             // 2*128*64 ushort
    unsigned short* bufA     = wpk2 + 2 * 128 * 64;              // N*128 ushort : xw1/xw2 (bf16)
    float*          bufB     = (float*)(bufA + (size_t)N * 128); // N*128 f32 : h1/h2

    const int B = 256;

    // 1) degree + in-degree count
    k_init<<<ceil_div_ll(N, B), B, 0, stream>>>(deg, count, N);
    k_deg_count<<<ceil_div_ll(E, B), B, 0, stream>>>(dst, ew, deg, count, E);
    k_rsqrt<<<ceil_div_ll(N, B), B, 0, stream>>>(deg, N);

    // 2) CSR build: parallel scan + counting-sort fill
    k_scan_a<<<NB_SCAN, SC_T, 0, stream>>>(count, bsum, N);
    k_scan_b<<<1, 64, 0, stream>>>(bsum, NB_SCAN);
    k_scan_c<<<NB_SCAN, SC_T, 0, stream>>>(count, rowptr, bsum, N);
    k_csr_fill<<<ceil_div_ll(E, B), B, 0, stream>>>(src, dst, ew, deg, count,
                                                    csr_src, csr_coef, E);

    // W pre-pack
    k_wpack<256, 128><<<(8 * 8 * 64 + B - 1) / B, B, 0, stream>>>(W1, wpk1);
    k_wpack<128, 64><<<(4 * 4 * 64 + B - 1) / B, B, 0, stream>>>(W2, wpk2);

    // 3) layer 1: xw1(bf16) = x @ W1 ; h1(f32) = relu(gather + b1)
    k_gemm_mfma<256, 128><<<ceil_div_ll(N, 64), 256, 0, stream>>>(x, wpk1, bufA, N);
    k_gather<128><<<ceil_div_ll(N, 4), 256, 0, stream>>>(
        bufA, rowptr, csr_src, csr_coef, deg, b1, bufB, N);

    // 4) layer 2: xw2(bf16) = h1 @ W2 ; h2(f32) = relu(gather + b2)
    k_gemm_mfma<128, 64><<<ceil_div_ll(N, 64), 256, 0, stream>>>(bufB, wpk2, bufA, N);
    k_gather<64><<<ceil_div_ll(N, 4), 256, 0, stream>>>(
        bufA, rowptr, csr_src, csr_coef, deg, b2, (float*)bufB, N);

    // 5) fused mean-pool + head
    k_pool_head<<<G, 256, 0, stream>>>(bufB, bat, Wfc, bfc, out, N);
}

// Round 7
// 443.506 us; speedup vs baseline: 11.8686x; 1.3424x over previous
//
#include <hip/hip_runtime.h>
#include <hip/hip_bf16.h>

// ---------------------------------------------------------------------------
// RewardGNN: 2-layer GCN (256->128->64) + mean-pool + linear head.
// Round 7: CSR build with ONE atomic per edge:
//   - packed u64 atomic: high32 = in-count, low32 = deg in 25-bit fixed point
//   - atomic return value = slot within dst row -> csr_fill has NO atomics
//   - CSR entry packed as int2{src, coef_bits}: one 8B store / 8B load
// GEMMs: bf16 split-precision MFMA; gathers read bf16 rows (round-6 design).
// ---------------------------------------------------------------------------

static inline int ceil_div_ll(long long a, int b) { return (int)((a + b - 1) / b); }

typedef __attribute__((ext_vector_type(8))) short bf16x8;
typedef __attribute__((ext_vector_type(4))) float f32x4;

#define FIX_SCALE 33554432.0f   // 2^25

__device__ inline unsigned short f2bf(float f) {
    __hip_bfloat16 h = __float2bfloat16(f);  // round-to-nearest-even
    return *reinterpret_cast<unsigned short*>(&h);
}
__device__ inline float bf2f(unsigned short u) {
    unsigned int x = ((unsigned int)u) << 16;
    return __uint_as_float(x);
}

// pk[i] = count<<32 | deg_fixed ; init deg=1.0 (self-loop), count=0
__global__ void k_init_pk(unsigned long long* __restrict__ pk, int n) {
    int i = blockIdx.x * blockDim.x + threadIdx.x;
    if (i < n) pk[i] = (unsigned long long)(1u << 25);
}

// one u64 atomic per edge; returned old high32 = slot within dst row
__global__ void k_deg_count(const int* __restrict__ dst, const float* __restrict__ ew,
                            unsigned long long* __restrict__ pk, int* __restrict__ slot, int E) {
    int e = blockIdx.x * blockDim.x + threadIdx.x;
    if (e < E) {
        unsigned int fx = __float2uint_rn(ew[e] * FIX_SCALE);
        unsigned long long old =
            atomicAdd(&pk[dst[e]], (1ull << 32) | (unsigned long long)fx);
        slot[e] = (int)(old >> 32);
    }
}

// dinv[i] = rsqrt(deg), count[i] = in-count
__global__ void k_finish(const unsigned long long* __restrict__ pk, float* __restrict__ dinv,
                         int* __restrict__ count, int n) {
    int i = blockIdx.x * blockDim.x + threadIdx.x;
    if (i < n) {
        unsigned long long v = pk[i];
        float deg = (float)(unsigned int)(v & 0xffffffffull) * (1.0f / FIX_SCALE);
        dinv[i] = (deg > 0.f) ? rsqrtf(deg) : 0.f;
        count[i] = (int)(v >> 32);
    }
}

// ------------------------- 3-phase parallel scan ---------------------------
constexpr int SC_T = 256;
constexpr int SC_PER = 16;
constexpr int SC_CHUNK = SC_T * SC_PER;

__global__ void k_scan_a(const int* __restrict__ count, int* __restrict__ bsum, int n) {
    __shared__ int lds[SC_T];
    int b = blockIdx.x, t = threadIdx.x;
    int base = b * SC_CHUNK + t * SC_PER;
    int s = 0;
#pragma unroll
    for (int k = 0; k < SC_PER; ++k) {
        int idx = base + k;
        if (idx < n) s += count[idx];
    }
    lds[t] = s;
    __syncthreads();
    for (int off = 128; off > 0; off >>= 1) {
        if (t < off) lds[t] += lds[t + off];
        __syncthreads();
    }
    if (t == 0) bsum[b] = lds[0];
}

__global__ void k_scan_b(int* __restrict__ bsum, int nb) {
    if (threadIdx.x == 0) {
        int run = 0;
        for (int i = 0; i < nb; ++i) { int c = bsum[i]; bsum[i] = run; run += c; }
    }
}

__global__ void k_scan_c(const int* __restrict__ count, int* __restrict__ rowptr,
                         const int* __restrict__ bsum, int n) {
    __shared__ int lds[SC_T];
    int b = blockIdx.x, t = threadIdx.x;
    int base = b * SC_CHUNK + t * SC_PER;
    int v[SC_PER];
    int s = 0;
#pragma unroll
    for (int k = 0; k < SC_PER; ++k) {
        int idx = base + k;
        v[k] = (idx < n) ? count[idx] : 0;
        s += v[k];
    }
    lds[t] = s;
    for (int off = 1; off < SC_T; off <<= 1) {
        __syncthreads();
        int tmp = (t >= off) ? lds[t - off] : 0;
        __syncthreads();
        lds[t] += tmp;
    }
    __syncthreads();
    int run = bsum[b] + lds[t] - s;
#pragma unroll
    for (int k = 0; k < SC_PER; ++k) {
        int idx = base + k;
        if (idx < n) {
            rowptr[idx] = run;
            run += v[k];
            if (idx == n - 1) rowptr[n] = run;
        }
    }
}

// Fill CSR without atomics: pos = rowptr[dst] + slot[e]; one int2 store.
__global__ void k_csr_fill(const int* __restrict__ src, const int* __restrict__ dst,
                           const float* __restrict__ ew, const float* __restrict__ dinv,
                           const int* __restrict__ rowptr, const int* __restrict__ slot,
                           int2* __restrict__ csr, int E) {
    int e = blockIdx.x * blockDim.x + threadIdx.x;
    if (e < E) {
        int s = src[e], d = dst[e];
        int pos = rowptr[d] + slot[e];
        float coef = dinv[s] * ew[e] * dinv[d];
        csr[pos] = make_int2(s, __float_as_int(coef));
    }
}

// ---------------------------------------------------------------------------
// W pre-pack into MFMA B-fragment layout (hi/lo bf16).
// ---------------------------------------------------------------------------
template <int KDIM, int ODIM>
__global__ void k_wpack(const float* __restrict__ W, unsigned short* __restrict__ wpk) {
    constexpr int NKS = KDIM / 32, NF = ODIM / 16;
    int t = blockIdx.x * blockDim.x + threadIdx.x;
    if (t >= NKS * NF * 64) return;
    int lane = t & 63;
    int nf   = (t >> 6) % NF;
    int ks   = t / (64 * NF);
    int col  = nf * 16 + (lane & 15);
    int kb   = ks * 32 + (lane >> 4) * 8;
    bf16x8 hi, lo;
#pragma unroll
    for (int i = 0; i < 8; ++i) {
        float w = W[(size_t)(kb + i) * ODIM + col];
        unsigned short h = f2bf(w);
        hi[i] = (short)h;
        lo[i] = (short)f2bf(w - bf2f(h));
    }
    size_t base = (size_t)t * 8;
    *(bf16x8*)(wpk + base) = hi;
    *(bf16x8*)(wpk + (size_t)KDIM * ODIM + base) = lo;
}

// ---------------------------------------------------------------------------
// GEMM via mfma_f32_16x16x32_bf16, split-precision; OUTPUT IS bf16.
// ---------------------------------------------------------------------------
template <int KDIM, int ODIM>
__global__ void k_gemm_mfma(const float* __restrict__ X,
                            const unsigned short* __restrict__ wpk,
                            unsigned short* __restrict__ Y, int n) {
    constexpr int NKS = KDIM / 32, NF = ODIM / 16;
    int wid  = threadIdx.x >> 6;
    int lane = threadIdx.x & 63;
    int rowbase = blockIdx.x * 64 + wid * 16;
    int arow = rowbase + (lane & 15);
    int kb0  = (lane >> 4) * 8;
    const unsigned short* wlo = wpk + (size_t)KDIM * ODIM;
    bool aok = (arow < n);
    const float* xr = X + (size_t)arow * KDIM + kb0;

    f32x4 acc[NF];
#pragma unroll
    for (int f = 0; f < NF; ++f) acc[f] = (f32x4){0.f, 0.f, 0.f, 0.f};

#pragma unroll
    for (int ks = 0; ks < NKS; ++ks) {
        f32x4 a0 = (f32x4){0.f, 0.f, 0.f, 0.f};
        f32x4 a1 = (f32x4){0.f, 0.f, 0.f, 0.f};
        if (aok) {
            a0 = *(const f32x4*)(xr + ks * 32);
            a1 = *(const f32x4*)(xr + ks * 32 + 4);
        }
        bf16x8 ahi, alo;
#pragma unroll
        for (int i = 0; i < 4; ++i) {
            unsigned short h0 = f2bf(a0[i]);
            ahi[i]     = (short)h0;
            alo[i]     = (short)f2bf(a0[i] - bf2f(h0));
            unsigned short h1 = f2bf(a1[i]);
            ahi[i + 4] = (short)h1;
            alo[i + 4] = (short)f2bf(a1[i] - bf2f(h1));
        }
#pragma unroll
        for (int f = 0; f < NF; ++f) {
            size_t fb = (((size_t)ks * NF + f) * 64 + lane) * 8;
            bf16x8 bhi = *(const bf16x8*)(wpk + fb);
            bf16x8 blo = *(const bf16x8*)(wlo + fb);
            acc[f] = __builtin_amdgcn_mfma_f32_16x16x32_bf16(ahi, bhi, acc[f], 0, 0, 0);
            acc[f] = __builtin_amdgcn_mfma_f32_16x16x32_bf16(alo, bhi, acc[f], 0, 0, 0);
            acc[f] = __builtin_amdgcn_mfma_f32_16x16x32_bf16(ahi, blo, acc[f], 0, 0, 0);
        }
    }

    int r0  = rowbase + (lane >> 4) * 4;
    int col = lane & 15;
#pragma unroll
    for (int f = 0; f < NF; ++f) {
#pragma unroll
        for (int i = 0; i < 4; ++i) {
            int r = r0 + i;
            if (r < n) Y[(size_t)r * ODIM + f * 16 + col] = f2bf(acc[f][i]);
        }
    }
}

// ---------------------------------------------------------------------------
// Gather (bf16 input rows, f32 accumulate/output), packed int2 CSR:
//   out[i] = relu( dinv[i]^2 * xw[i] + sum_e coef_e * xw[src_e] + bias )
// One wave per node; 8-deep unroll for memory-level parallelism.
// ---------------------------------------------------------------------------
template <int F>
__global__ void k_gather(const unsigned short* __restrict__ xw, const int* __restrict__ rowptr,
                         const int2* __restrict__ csr,
                         const float* __restrict__ dinv, const float* __restrict__ bias,
                         float* __restrict__ out, int n) {
    int wave = threadIdx.x >> 6;
    int lane = threadIdx.x & 63;
    int i = blockIdx.x * 4 + wave;
    if (i >= n) return;

    float dv = dinv[i];
    float sl = dv * dv;
    int e0 = __builtin_amdgcn_readfirstlane(rowptr[i]);
    int e1 = __builtin_amdgcn_readfirstlane(rowptr[i + 1]);

    if constexpr (F == 128) {
        const unsigned int* base = (const unsigned int*)xw;  // row stride 64 u32
        unsigned int su = base[(size_t)i * 64 + lane];
        float ax0 = bf2f((unsigned short)(su & 0xffff)) * sl;
        float ay0 = bf2f((unsigned short)(su >> 16)) * sl;
        float ax1 = 0.f, ay1 = 0.f, ax2 = 0.f, ay2 = 0.f, ax3 = 0.f, ay3 = 0.f;
        int e = e0;
        for (; e + 8 <= e1; e += 8) {
            int2 p0 = csr[e + 0], p1 = csr[e + 1], p2 = csr[e + 2], p3 = csr[e + 3];
            int2 p4 = csr[e + 4], p5 = csr[e + 5], p6 = csr[e + 6], p7 = csr[e + 7];
            unsigned int u0 = base[(size_t)p0.x * 64 + lane];
            unsigned int u1 = base[(size_t)p1.x * 64 + lane];
            unsigned int u2 = base[(size_t)p2.x * 64 + lane];
            unsigned int u3 = base[(size_t)p3.x * 64 + lane];
            unsigned int u4 = base[(size_t)p4.x * 64 + lane];
            unsigned int u5 = base[(size_t)p5.x * 64 + lane];
            unsigned int u6 = base[(size_t)p6.x * 64 + lane];
            unsigned int u7 = base[(size_t)p7.x * 64 + lane];
            float c0 = __int_as_float(p0.y), c1 = __int_as_float(p1.y);
            float c2 = __int_as_float(p2.y), c3 = __int_as_float(p3.y);
            float c4 = __int_as_float(p4.y), c5 = __int_as_float(p5.y);
            float c6 = __int_as_float(p6.y), c7 = __int_as_float(p7.y);
            ax0 += c0 * bf2f((unsigned short)(u0 & 0xffff)); ay0 += c0 * bf2f((unsigned short)(u0 >> 16));
            ax1 += c1 * bf2f((unsigned short)(u1 & 0xffff)); ay1 += c1 * bf2f((unsigned short)(u1 >> 16));
            ax2 += c2 * bf2f((unsigned short)(u2 & 0xffff)); ay2 += c2 * bf2f((unsigned short)(u2 >> 16));
            ax3 += c3 * bf2f((unsigned short)(u3 & 0xffff)); ay3 += c3 * bf2f((unsigned short)(u3 >> 16));
            ax0 += c4 * bf2f((unsigned short)(u4 & 0xffff)); ay0 += c4 * bf2f((unsigned short)(u4 >> 16));
            ax1 += c5 * bf2f((unsigned short)(u5 & 0xffff)); ay1 += c5 * bf2f((unsigned short)(u5 >> 16));
            ax2 += c6 * bf2f((unsigned short)(u6 & 0xffff)); ay2 += c6 * bf2f((unsigned short)(u6 >> 16));
            ax3 += c7 * bf2f((unsigned short)(u7 & 0xffff)); ay3 += c7 * bf2f((unsigned short)(u7 >> 16));
        }
        for (; e + 2 <= e1; e += 2) {
            int2 p0 = csr[e + 0], p1 = csr[e + 1];
            unsigned int u0 = base[(size_t)p0.x * 64 + lane];
            unsigned int u1 = base[(size_t)p1.x * 64 + lane];
            float c0 = __int_as_float(p0.y), c1 = __int_as_float(p1.y);
            ax0 += c0 * bf2f((unsigned short)(u0 & 0xffff)); ay0 += c0 * bf2f((unsigned short)(u0 >> 16));
            ax1 += c1 * bf2f((unsigned short)(u1 & 0xffff)); ay1 += c1 * bf2f((unsigned short)(u1 >> 16));
        }
        if (e < e1) {
            int2 p0 = csr[e];
            unsigned int u0 = base[(size_t)p0.x * 64 + lane];
            float c0 = __int_as_float(p0.y);
            ax0 += c0 * bf2f((unsigned short)(u0 & 0xffff)); ay0 += c0 * bf2f((unsigned short)(u0 >> 16));
        }
        float2 bb = *((const float2*)bias + lane);
        float rx = fmaxf((ax0 + ax1) + (ax2 + ax3) + bb.x, 0.f);
        float ry = fmaxf((ay0 + ay1) + (ay2 + ay3) + bb.y, 0.f);
        *((float2*)(out + (size_t)i * F) + lane) = make_float2(rx, ry);
    } else {  // F == 64
        float a0 = bf2f(xw[(size_t)i * 64 + lane]) * sl;
        float a1 = 0.f, a2 = 0.f, a3 = 0.f;
        int e = e0;
        for (; e + 8 <= e1; e += 8) {
            int2 p0 = csr[e + 0], p1 = csr[e + 1], p2 = csr[e + 2], p3 = csr[e + 3];
            int2 p4 = csr[e + 4], p5 = csr[e + 5], p6 = csr[e + 6], p7 = csr[e + 7];
            float v0 = bf2f(xw[(size_t)p0.x * 64 + lane]);
            float v1 = bf2f(xw[(size_t)p1.x * 64 + lane]);
            float v2 = bf2f(xw[(size_t)p2.x * 64 + lane]);
            float v3 = bf2f(xw[(size_t)p3.x * 64 + lane]);
            float v4 = bf2f(xw[(size_t)p4.x * 64 + lane]);
            float v5 = bf2f(xw[(size_t)p5.x * 64 + lane]);
            float v6 = bf2f(xw[(size_t)p6.x * 64 + lane]);
            float v7 = bf2f(xw[(size_t)p7.x * 64 + lane]);
            a0 += __int_as_float(p0.y) * v0; a1 += __int_as_float(p1.y) * v1;
            a2 += __int_as_float(p2.y) * v2; a3 += __int_as_float(p3.y) * v3;
            a0 += __int_as_float(p4.y) * v4; a1 += __int_as_float(p5.y) * v5;
            a2 += __int_as_float(p6.y) * v6; a3 += __int_as_float(p7.y) * v7;
        }
        for (; e + 2 <= e1; e += 2) {
            int2 p0 = csr[e + 0], p1 = csr[e + 1];
            a0 += __int_as_float(p0.y) * bf2f(xw[(size_t)p0.x * 64 + lane]);
            a1 += __int_as_float(p1.y) * bf2f(xw[(size_t)p1.x * 64 + lane]);
        }
        if (e < e1) {
            int2 p0 = csr[e];
            a0 += __int_as_float(p0.y) * bf2f(xw[(size_t)p0.x * 64 + lane]);
        }
        float res = fmaxf((a0 + a1) + (a2 + a3) + bias[lane], 0.f);
        out[(size_t)i * 64 + lane] = res;
    }
}

// ---------------------------------------------------------------------------
// Fused mean-pool + head: one block per graph (batch is sorted).
// ---------------------------------------------------------------------------
__global__ void k_pool_head(const float* __restrict__ h2, const int* __restrict__ batch,
                            const float* __restrict__ Wfc, const float* __restrict__ bfc,
                            float* __restrict__ out, int n) {
    int g = blockIdx.x;
    __shared__ int bounds[2];
    __shared__ float part[256];
    int t = threadIdx.x;
    if (t < 2) {
        int target = g + t;
        int lo = 0, hi = n;
        while (lo < hi) {
            int mid = (lo + hi) >> 1;
            if (batch[mid] < target) lo = mid + 1; else hi = mid;
        }
        bounds[t] = lo;
    }
    __syncthreads();
    int lo = bounds[0], hi = bounds[1];
    int f = t & 63, rg = t >> 6;
    float acc = 0.f;
    for (int r = lo + rg; r < hi; r += 4) acc += h2[(size_t)r * 64 + f];
    part[t] = acc;
    __syncthreads();
    if (t < 64) {
        float s = part[t] + part[t + 64] + part[t + 128] + part[t + 192];
        float cntf = (float)(hi - lo);
        float v = (s / fmaxf(cntf, 1.0f)) * Wfc[f];
#pragma unroll
        for (int o = 32; o > 0; o >>= 1) v += __shfl_down(v, o);
        if (t == 0) out[g] = v + bfc[0];
    }
}

extern "C" void kernel_launch(void* const* d_in, const int* in_sizes, int n_in,
                              void* d_out, int out_size, void* d_ws, size_t ws_size,
                              hipStream_t stream) {
    const float* x    = (const float*)d_in[0];
    const int*   ei   = (const int*)d_in[1];
    const float* ew   = (const float*)d_in[2];
    const int*   bat  = (const int*)d_in[3];
    const float* W1   = (const float*)d_in[4];
    const float* b1   = (const float*)d_in[5];
    const float* W2   = (const float*)d_in[6];
    const float* b2   = (const float*)d_in[7];
    const float* Wfc  = (const float*)d_in[8];
    const float* bfc  = (const float*)d_in[9];
    float*       out  = (float*)d_out;

    const int N = in_sizes[0] / 256;
    const int E = in_sizes[2];
    const int G = out_size;

    const int* src = ei;
    const int* dst = ei + E;

    const int NB_SCAN = (N + SC_CHUNK - 1) / SC_CHUNK;

    // workspace layout (f32-unit offsets; chunks 8B-aligned)
    const int Npad = (N + 4) & ~3;
    unsigned long long* pk       = (unsigned long long*)d_ws;       // N u64
    float*              dinv     = (float*)(pk + Npad);             // N
    int*                count    = (int*)(dinv + Npad);             // N
    int*                rowptr   = count + Npad;                    // N+1
    int*                bsum     = rowptr + Npad;                   // NB_SCAN
    int*                slot     = bsum + ((NB_SCAN + 4) & ~3);     // E
    int2*               csr      = (int2*)(slot + ((E + 4) & ~3)); // E int2
    unsigned short*     wpk1     = (unsigned short*)(csr + E);     // 2*256*128
    unsigned short*     wpk2     = wpk1 + 2 * 256 * 128;            // 2*128*64
    unsigned short*     bufA     = wpk2 + 2 * 128 * 64;             // N*128 bf16
    float*              bufB     = (float*)(bufA + (size_t)N * 128); // N*128 f32

    const int B = 256;

    // 1) packed degree + count (+ per-edge slot), one atomic per edge
    k_init_pk<<<ceil_div_ll(N, B), B, 0, stream>>>(pk, N);
    k_deg_count<<<ceil_div_ll(E, B), B, 0, stream>>>(dst, ew, pk, slot, E);
    k_finish<<<ceil_div_ll(N, B), B, 0, stream>>>(pk, dinv, count, N);

    // 2) CSR build: parallel scan + atomic-free fill
    k_scan_a<<<NB_SCAN, SC_T, 0, stream>>>(count, bsum, N);
    k_scan_b<<<1, 64, 0, stream>>>(bsum, NB_SCAN);
    k_scan_c<<<NB_SCAN, SC_T, 0, stream>>>(count, rowptr, bsum, N);
    k_csr_fill<<<ceil_div_ll(E, B), B, 0, stream>>>(src, dst, ew, dinv, rowptr,
                                                    slot, csr, E);

    // W pre-pack
    k_wpack<256, 128><<<(8 * 8 * 64 + B - 1) / B, B, 0, stream>>>(W1, wpk1);
    k_wpack<128, 64><<<(4 * 4 * 64 + B - 1) / B, B, 0, stream>>>(W2, wpk2);

    // 3) layer 1: xw1(bf16) = x @ W1 ; h1(f32) = relu(gather + b1)
    k_gemm_mfma<256, 128><<<ceil_div_ll(N, 64), 256, 0, stream>>>(x, wpk1, bufA, N);
    k_gather<128><<<ceil_div_ll(N, 4), 256, 0, stream>>>(
        bufA, rowptr, csr, dinv, b1, bufB, N);

    // 4) layer 2: xw2(bf16) = h1 @ W2 ; h2(f32) = relu(gather + b2)
    k_gemm_mfma<128, 64><<<ceil_div_ll(N, 64), 256, 0, stream>>>(bufB, wpk2, bufA, N);
    k_gather<64><<<ceil_div_ll(N, 4), 256, 0, stream>>>(
        bufA, rowptr, csr, dinv, b2, bufB, N);

    // 5) fused mean-pool + head
    k_pool_head<<<G, 256, 0, stream>>>(bufB, bat, Wfc, bfc, out, N);
}

// Round 9
// 355.325 us; speedup vs baseline: 14.8141x; 1.2482x over previous
//
#include <hip/hip_runtime.h>
#include <hip/hip_bf16.h>

// ---------------------------------------------------------------------------
// RewardGNN: 2-layer GCN (256->128->64) + mean-pool + linear head.
// Round 9: fix round-8's k_fill grid bug (zeroed only 256 of G*64 sums ->
//   atomics accumulated across graph replays -> determinism check failed).
// Two-stage mean-pool; one-u64-atomic CSR build; bf16 split-precision MFMA
// GEMMs; gathers read bf16 rows.
// ---------------------------------------------------------------------------

static inline int ceil_div_ll(long long a, int b) { return (int)((a + b - 1) / b); }

typedef __attribute__((ext_vector_type(8))) short bf16x8;
typedef __attribute__((ext_vector_type(4))) float f32x4;

#define FIX_SCALE 33554432.0f   // 2^25

__device__ inline unsigned short f2bf(float f) {
    __hip_bfloat16 h = __float2bfloat16(f);  // round-to-nearest-even
    return *reinterpret_cast<unsigned short*>(&h);
}
__device__ inline float bf2f(unsigned short u) {
    unsigned int x = ((unsigned int)u) << 16;
    return __uint_as_float(x);
}

// pk[i] = count<<32 | deg_fixed ; init deg=1.0 (self-loop), count=0
__global__ void k_init_pk(unsigned long long* __restrict__ pk, int n) {
    int i = blockIdx.x * blockDim.x + threadIdx.x;
    if (i < n) pk[i] = (unsigned long long)(1u << 25);
}

// one u64 atomic per edge; returned old high32 = slot within dst row
__global__ void k_deg_count(const int* __restrict__ dst, const float* __restrict__ ew,
                            unsigned long long* __restrict__ pk, int* __restrict__ slot, int E) {
    int e = blockIdx.x * blockDim.x + threadIdx.x;
    if (e < E) {
        unsigned int fx = __float2uint_rn(ew[e] * FIX_SCALE);
        unsigned long long old =
            atomicAdd(&pk[dst[e]], (1ull << 32) | (unsigned long long)fx);
        slot[e] = (int)(old >> 32);
    }
}

// dinv[i] = rsqrt(deg), count[i] = in-count
__global__ void k_finish(const unsigned long long* __restrict__ pk, float* __restrict__ dinv,
                         int* __restrict__ count, int n) {
    int i = blockIdx.x * blockDim.x + threadIdx.x;
    if (i < n) {
        unsigned long long v = pk[i];
        float deg = (float)(unsigned int)(v & 0xffffffffull) * (1.0f / FIX_SCALE);
        dinv[i] = (deg > 0.f) ? rsqrtf(deg) : 0.f;
        count[i] = (int)(v >> 32);
    }
}

// ------------------------- 3-phase parallel scan ---------------------------
constexpr int SC_T = 256;
constexpr int SC_PER = 16;
constexpr int SC_CHUNK = SC_T * SC_PER;

__global__ void k_scan_a(const int* __restrict__ count, int* __restrict__ bsum, int n) {
    __shared__ int lds[SC_T];
    int b = blockIdx.x, t = threadIdx.x;
    int base = b * SC_CHUNK + t * SC_PER;
    int s = 0;
#pragma unroll
    for (int k = 0; k < SC_PER; ++k) {
        int idx = base + k;
        if (idx < n) s += count[idx];
    }
    lds[t] = s;
    __syncthreads();
    for (int off = 128; off > 0; off >>= 1) {
        if (t < off) lds[t] += lds[t + off];
        __syncthreads();
    }
    if (t == 0) bsum[b] = lds[0];
}

__global__ void k_scan_b(int* __restrict__ bsum, int nb) {
    if (threadIdx.x == 0) {
        int run = 0;
        for (int i = 0; i < nb; ++i) { int c = bsum[i]; bsum[i] = run; run += c; }
    }
}

__global__ void k_scan_c(const int* __restrict__ count, int* __restrict__ rowptr,
                         const int* __restrict__ bsum, int n) {
    __shared__ int lds[SC_T];
    int b = blockIdx.x, t = threadIdx.x;
    int base = b * SC_CHUNK + t * SC_PER;
    int v[SC_PER];
    int s = 0;
#pragma unroll
    for (int k = 0; k < SC_PER; ++k) {
        int idx = base + k;
        v[k] = (idx < n) ? count[idx] : 0;
        s += v[k];
    }
    lds[t] = s;
    for (int off = 1; off < SC_T; off <<= 1) {
        __syncthreads();
        int tmp = (t >= off) ? lds[t - off] : 0;
        __syncthreads();
        lds[t] += tmp;
    }
    __syncthreads();
    int run = bsum[b] + lds[t] - s;
#pragma unroll
    for (int k = 0; k < SC_PER; ++k) {
        int idx = base + k;
        if (idx < n) {
            rowptr[idx] = run;
            run += v[k];
            if (idx == n - 1) rowptr[n] = run;
        }
    }
}

// Fill CSR without atomics: pos = rowptr[dst] + slot[e]; one int2 store.
__global__ void k_csr_fill(const int* __restrict__ src, const int* __restrict__ dst,
                           const float* __restrict__ ew, const float* __restrict__ dinv,
                           const int* __restrict__ rowptr, const int* __restrict__ slot,
                           int2* __restrict__ csr, int E) {
    int e = blockIdx.x * blockDim.x + threadIdx.x;
    if (e < E) {
        int s = src[e], d = dst[e];
        int pos = rowptr[d] + slot[e];
        float coef = dinv[s] * ew[e] * dinv[d];
        csr[pos] = make_int2(s, __float_as_int(coef));
    }
}

// ---------------------------------------------------------------------------
// W pre-pack into MFMA B-fragment layout (hi/lo bf16).
// ---------------------------------------------------------------------------
template <int KDIM, int ODIM>
__global__ void k_wpack(const float* __restrict__ W, unsigned short* __restrict__ wpk) {
    constexpr int NKS = KDIM / 32, NF = ODIM / 16;
    int t = blockIdx.x * blockDim.x + threadIdx.x;
    if (t >= NKS * NF * 64) return;
    int lane = t & 63;
    int nf   = (t >> 6) % NF;
    int ks   = t / (64 * NF);
    int col  = nf * 16 + (lane & 15);
    int kb   = ks * 32 + (lane >> 4) * 8;
    bf16x8 hi, lo;
#pragma unroll
    for (int i = 0; i < 8; ++i) {
        float w = W[(size_t)(kb + i) * ODIM + col];
        unsigned short h = f2bf(w);
        hi[i] = (short)h;
        lo[i] = (short)f2bf(w - bf2f(h));
    }
    size_t base = (size_t)t * 8;
    *(bf16x8*)(wpk + base) = hi;
    *(bf16x8*)(wpk + (size_t)KDIM * ODIM + base) = lo;
}

// ---------------------------------------------------------------------------
// GEMM via mfma_f32_16x16x32_bf16, split-precision; OUTPUT IS bf16.
// ---------------------------------------------------------------------------
template <int KDIM, int ODIM>
__global__ void k_gemm_mfma(const float* __restrict__ X,
                            const unsigned short* __restrict__ wpk,
                            unsigned short* __restrict__ Y, int n) {
    constexpr int NKS = KDIM / 32, NF = ODIM / 16;
    int wid  = threadIdx.x >> 6;
    int lane = threadIdx.x & 63;
    int rowbase = blockIdx.x * 64 + wid * 16;
    int arow = rowbase + (lane & 15);
    int kb0  = (lane >> 4) * 8;
    const unsigned short* wlo = wpk + (size_t)KDIM * ODIM;
    bool aok = (arow < n);
    const float* xr = X + (size_t)arow * KDIM + kb0;

    f32x4 acc[NF];
#pragma unroll
    for (int f = 0; f < NF; ++f) acc[f] = (f32x4){0.f, 0.f, 0.f, 0.f};

#pragma unroll
    for (int ks = 0; ks < NKS; ++ks) {
        f32x4 a0 = (f32x4){0.f, 0.f, 0.f, 0.f};
        f32x4 a1 = (f32x4){0.f, 0.f, 0.f, 0.f};
        if (aok) {
            a0 = *(const f32x4*)(xr + ks * 32);
            a1 = *(const f32x4*)(xr + ks * 32 + 4);
        }
        bf16x8 ahi, alo;
#pragma unroll
        for (int i = 0; i < 4; ++i) {
            unsigned short h0 = f2bf(a0[i]);
            ahi[i]     = (short)h0;
            alo[i]     = (short)f2bf(a0[i] - bf2f(h0));
            unsigned short h1 = f2bf(a1[i]);
            ahi[i + 4] = (short)h1;
            alo[i + 4] = (short)f2bf(a1[i] - bf2f(h1));
        }
#pragma unroll
        for (int f = 0; f < NF; ++f) {
            size_t fb = (((size_t)ks * NF + f) * 64 + lane) * 8;
            bf16x8 bhi = *(const bf16x8*)(wpk + fb);
            bf16x8 blo = *(const bf16x8*)(wlo + fb);
            acc[f] = __builtin_amdgcn_mfma_f32_16x16x32_bf16(ahi, bhi, acc[f], 0, 0, 0);
            acc[f] = __builtin_amdgcn_mfma_f32_16x16x32_bf16(alo, bhi, acc[f], 0, 0, 0);
            acc[f] = __builtin_amdgcn_mfma_f32_16x16x32_bf16(ahi, blo, acc[f], 0, 0, 0);
        }
    }

    int r0  = rowbase + (lane >> 4) * 4;
    int col = lane & 15;
#pragma unroll
    for (int f = 0; f < NF; ++f) {
#pragma unroll
        for (int i = 0; i < 4; ++i) {
            int r = r0 + i;
            if (r < n) Y[(size_t)r * ODIM + f * 16 + col] = f2bf(acc[f][i]);
        }
    }
}

// ---------------------------------------------------------------------------
// Gather (bf16 input rows, f32 accumulate/output), packed int2 CSR:
//   out[i] = relu( dinv[i]^2 * xw[i] + sum_e coef_e * xw[src_e] + bias )
// One wave per node; 8-deep unroll for memory-level parallelism.
// ---------------------------------------------------------------------------
template <int F>
__global__ void k_gather(const unsigned short* __restrict__ xw, const int* __restrict__ rowptr,
                         const int2* __restrict__ csr,
                         const float* __restrict__ dinv, const float* __restrict__ bias,
                         float* __restrict__ out, int n) {
    int wave = threadIdx.x >> 6;
    int lane = threadIdx.x & 63;
    int i = blockIdx.x * 4 + wave;
    if (i >= n) return;

    float dv = dinv[i];
    float sl = dv * dv;
    int e0 = __builtin_amdgcn_readfirstlane(rowptr[i]);
    int e1 = __builtin_amdgcn_readfirstlane(rowptr[i + 1]);

    if constexpr (F == 128) {
        const unsigned int* base = (const unsigned int*)xw;  // row stride 64 u32
        unsigned int su = base[(size_t)i * 64 + lane];
        float ax0 = bf2f((unsigned short)(su & 0xffff)) * sl;
        float ay0 = bf2f((unsigned short)(su >> 16)) * sl;
        float ax1 = 0.f, ay1 = 0.f, ax2 = 0.f, ay2 = 0.f, ax3 = 0.f, ay3 = 0.f;
        int e = e0;
        for (; e + 8 <= e1; e += 8) {
            int2 p0 = csr[e + 0], p1 = csr[e + 1], p2 = csr[e + 2], p3 = csr[e + 3];
            int2 p4 = csr[e + 4], p5 = csr[e + 5], p6 = csr[e + 6], p7 = csr[e + 7];
            unsigned int u0 = base[(size_t)p0.x * 64 + lane];
            unsigned int u1 = base[(size_t)p1.x * 64 + lane];
            unsigned int u2 = base[(size_t)p2.x * 64 + lane];
            unsigned int u3 = base[(size_t)p3.x * 64 + lane];
            unsigned int u4 = base[(size_t)p4.x * 64 + lane];
            unsigned int u5 = base[(size_t)p5.x * 64 + lane];
            unsigned int u6 = base[(size_t)p6.x * 64 + lane];
            unsigned int u7 = base[(size_t)p7.x * 64 + lane];
            float c0 = __int_as_float(p0.y), c1 = __int_as_float(p1.y);
            float c2 = __int_as_float(p2.y), c3 = __int_as_float(p3.y);
            float c4 = __int_as_float(p4.y), c5 = __int_as_float(p5.y);
            float c6 = __int_as_float(p6.y), c7 = __int_as_float(p7.y);
            ax0 += c0 * bf2f((unsigned short)(u0 & 0xffff)); ay0 += c0 * bf2f((unsigned short)(u0 >> 16));
            ax1 += c1 * bf2f((unsigned short)(u1 & 0xffff)); ay1 += c1 * bf2f((unsigned short)(u1 >> 16));
            ax2 += c2 * bf2f((unsigned short)(u2 & 0xffff)); ay2 += c2 * bf2f((unsigned short)(u2 >> 16));
            ax3 += c3 * bf2f((unsigned short)(u3 & 0xffff)); ay3 += c3 * bf2f((unsigned short)(u3 >> 16));
            ax0 += c4 * bf2f((unsigned short)(u4 & 0xffff)); ay0 += c4 * bf2f((unsigned short)(u4 >> 16));
            ax1 += c5 * bf2f((unsigned short)(u5 & 0xffff)); ay1 += c5 * bf2f((unsigned short)(u5 >> 16));
            ax2 += c6 * bf2f((unsigned short)(u6 & 0xffff)); ay2 += c6 * bf2f((unsigned short)(u6 >> 16));
            ax3 += c7 * bf2f((unsigned short)(u7 & 0xffff)); ay3 += c7 * bf2f((unsigned short)(u7 >> 16));
        }
        for (; e + 2 <= e1; e += 2) {
            int2 p0 = csr[e + 0], p1 = csr[e + 1];
            unsigned int u0 = base[(size_t)p0.x * 64 + lane];
            unsigned int u1 = base[(size_t)p1.x * 64 + lane];
            float c0 = __int_as_float(p0.y), c1 = __int_as_float(p1.y);
            ax0 += c0 * bf2f((unsigned short)(u0 & 0xffff)); ay0 += c0 * bf2f((unsigned short)(u0 >> 16));
            ax1 += c1 * bf2f((unsigned short)(u1 & 0xffff)); ay1 += c1 * bf2f((unsigned short)(u1 >> 16));
        }
        if (e < e1) {
            int2 p0 = csr[e];
            unsigned int u0 = base[(size_t)p0.x * 64 + lane];
            float c0 = __int_as_float(p0.y);
            ax0 += c0 * bf2f((unsigned short)(u0 & 0xffff)); ay0 += c0 * bf2f((unsigned short)(u0 >> 16));
        }
        float2 bb = *((const float2*)bias + lane);
        float rx = fmaxf((ax0 + ax1) + (ax2 + ax3) + bb.x, 0.f);
        float ry = fmaxf((ay0 + ay1) + (ay2 + ay3) + bb.y, 0.f);
        *((float2*)(out + (size_t)i * F) + lane) = make_float2(rx, ry);
    } else {  // F == 64
        float a0 = bf2f(xw[(size_t)i * 64 + lane]) * sl;
        float a1 = 0.f, a2 = 0.f, a3 = 0.f;
        int e = e0;
        for (; e + 8 <= e1; e += 8) {
            int2 p0 = csr[e + 0], p1 = csr[e + 1], p2 = csr[e + 2], p3 = csr[e + 3];
            int2 p4 = csr[e + 4], p5 = csr[e + 5], p6 = csr[e + 6], p7 = csr[e + 7];
            float v0 = bf2f(xw[(size_t)p0.x * 64 + lane]);
            float v1 = bf2f(xw[(size_t)p1.x * 64 + lane]);
            float v2 = bf2f(xw[(size_t)p2.x * 64 + lane]);
            float v3 = bf2f(xw[(size_t)p3.x * 64 + lane]);
            float v4 = bf2f(xw[(size_t)p4.x * 64 + lane]);
            float v5 = bf2f(xw[(size_t)p5.x * 64 + lane]);
            float v6 = bf2f(xw[(size_t)p6.x * 64 + lane]);
            float v7 = bf2f(xw[(size_t)p7.x * 64 + lane]);
            a0 += __int_as_float(p0.y) * v0; a1 += __int_as_float(p1.y) * v1;
            a2 += __int_as_float(p2.y) * v2; a3 += __int_as_float(p3.y) * v3;
            a0 += __int_as_float(p4.y) * v4; a1 += __int_as_float(p5.y) * v5;
            a2 += __int_as_float(p6.y) * v6; a3 += __int_as_float(p7.y) * v7;
        }
        for (; e + 2 <= e1; e += 2) {
            int2 p0 = csr[e + 0], p1 = csr[e + 1];
            a0 += __int_as_float(p0.y) * bf2f(xw[(size_t)p0.x * 64 + lane]);
            a1 += __int_as_float(p1.y) * bf2f(xw[(size_t)p1.x * 64 + lane]);
        }
        if (e < e1) {
            int2 p0 = csr[e];
            a0 += __int_as_float(p0.y) * bf2f(xw[(size_t)p0.x * 64 + lane]);
        }
        float res = fmaxf((a0 + a1) + (a2 + a3) + bias[lane], 0.f);
        out[(size_t)i * 64 + lane] = res;
    }
}

// ---------------------------------------------------------------------------
// Two-stage mean-pool + head.
// ---------------------------------------------------------------------------
__global__ void k_fill(float* __restrict__ p, int n, float v) {
    int i = blockIdx.x * blockDim.x + threadIdx.x;
    if (i < n) p[i] = v;
}

// Stage 1: 1024 blocks; block owns rows [lo,hi); thread owns feature f,
// row-group rg; local accumulate, flush on sorted-batch boundary.
__global__ void k_pool1(const float* __restrict__ h2, const int* __restrict__ batch,
                        float* __restrict__ sums, int n) {
    int b = blockIdx.x, t = threadIdx.x;
    int chunk = (n + gridDim.x - 1) / gridDim.x;
    int lo = b * chunk, hi = min(lo + chunk, n);
    if (lo >= hi) return;
    int f = t & 63, rg = t >> 6;  // 4 row-groups
    float acc = 0.f;
    int cur = -1;
    for (int r = lo + rg; r < hi; r += 4) {
        int g = batch[r];
        if (g != cur) {
            if (cur >= 0) atomicAdd(&sums[cur * 64 + f], acc);
            acc = 0.f;
            cur = g;
        }
        acc += h2[(size_t)r * 64 + f];
    }
    if (cur >= 0) atomicAdd(&sums[cur * 64 + f], acc);
}

// Stage 2: one wave per graph; count via binary search on sorted batch.
__global__ void k_head(const float* __restrict__ sums, const int* __restrict__ batch,
                       const float* __restrict__ Wfc, const float* __restrict__ bfc,
                       float* __restrict__ out, int n) {
    int g = blockIdx.x;
    int f = threadIdx.x;  // 64 threads = 1 wave
    int lo0 = 0, hi0 = n;
    while (lo0 < hi0) { int m = (lo0 + hi0) >> 1; if (batch[m] < g) lo0 = m + 1; else hi0 = m; }
    int lo1 = lo0, hi1 = n;
    while (lo1 < hi1) { int m = (lo1 + hi1) >> 1; if (batch[m] < g + 1) lo1 = m + 1; else hi1 = m; }
    float cnt = (float)(lo1 - lo0);
    float v = sums[g * 64 + f] * Wfc[f];
#pragma unroll
    for (int o = 32; o > 0; o >>= 1) v += __shfl_down(v, o);
    if (f == 0) out[g] = v / fmaxf(cnt, 1.0f) + bfc[0];
}

extern "C" void kernel_launch(void* const* d_in, const int* in_sizes, int n_in,
                              void* d_out, int out_size, void* d_ws, size_t ws_size,
                              hipStream_t stream) {
    const float* x    = (const float*)d_in[0];
    const int*   ei   = (const int*)d_in[1];
    const float* ew   = (const float*)d_in[2];
    const int*   bat  = (const int*)d_in[3];
    const float* W1   = (const float*)d_in[4];
    const float* b1   = (const float*)d_in[5];
    const float* W2   = (const float*)d_in[6];
    const float* b2   = (const float*)d_in[7];
    const float* Wfc  = (const float*)d_in[8];
    const float* bfc  = (const float*)d_in[9];
    float*       out  = (float*)d_out;

    const int N = in_sizes[0] / 256;
    const int E = in_sizes[2];
    const int G = out_size;

    const int* src = ei;
    const int* dst = ei + E;

    const int NB_SCAN = (N + SC_CHUNK - 1) / SC_CHUNK;

    // workspace layout (8B-aligned chunks)
    const int Npad = (N + 4) & ~3;
    unsigned long long* pk       = (unsigned long long*)d_ws;        // N u64
    float*              dinv     = (float*)(pk + Npad);              // N
    int*                count    = (int*)(dinv + Npad);              // N
    int*                rowptr   = count + Npad;                     // N+1
    int*                bsum     = rowptr + Npad;                    // NB_SCAN
    int*                slot     = bsum + ((NB_SCAN + 4) & ~3);      // E
    int2*               csr      = (int2*)(slot + ((E + 4) & ~3));  // E int2
    unsigned short*     wpk1     = (unsigned short*)(csr + E);      // 2*256*128
    unsigned short*     wpk2     = wpk1 + 2 * 256 * 128;             // 2*128*64
    float*              sums     = (float*)(wpk2 + 2 * 128 * 64);   // G*64
    unsigned short*     bufA     = (unsigned short*)(sums + ((G * 64 + 4) & ~3)); // N*128 bf16
    float*              bufB     = (float*)(bufA + (size_t)N * 128); // N*128 f32

    const int B = 256;

    // 1) packed degree + count (+ per-edge slot), one atomic per edge
    k_init_pk<<<ceil_div_ll(N, B), B, 0, stream>>>(pk, N);
    k_deg_count<<<ceil_div_ll(E, B), B, 0, stream>>>(dst, ew, pk, slot, E);
    k_finish<<<ceil_div_ll(N, B), B, 0, stream>>>(pk, dinv, count, N);

    // 2) CSR build: parallel scan + atomic-free fill
    k_scan_a<<<NB_SCAN, SC_T, 0, stream>>>(count, bsum, N);
    k_scan_b<<<1, 64, 0, stream>>>(bsum, NB_SCAN);
    k_scan_c<<<NB_SCAN, SC_T, 0, stream>>>(count, rowptr, bsum, N);
    k_csr_fill<<<ceil_div_ll(E, B), B, 0, stream>>>(src, dst, ew, dinv, rowptr,
                                                    slot, csr, E);

    // W pre-pack
    k_wpack<256, 128><<<(8 * 8 * 64 + B - 1) / B, B, 0, stream>>>(W1, wpk1);
    k_wpack<128, 64><<<(4 * 4 * 64 + B - 1) / B, B, 0, stream>>>(W2, wpk2);

    // 3) layer 1: xw1(bf16) = x @ W1 ; h1(f32) = relu(gather + b1)
    k_gemm_mfma<256, 128><<<ceil_div_ll(N, 64), 256, 0, stream>>>(x, wpk1, bufA, N);
    k_gather<128><<<ceil_div_ll(N, 4), 256, 0, stream>>>(
        bufA, rowptr, csr, dinv, b1, bufB, N);

    // 4) layer 2: xw2(bf16) = h1 @ W2 ; h2(f32) = relu(gather + b2)
    k_gemm_mfma<128, 64><<<ceil_div_ll(N, 64), 256, 0, stream>>>(bufB, wpk2, bufA, N);
    k_gather<64><<<ceil_div_ll(N, 4), 256, 0, stream>>>(
        bufA, rowptr, csr, dinv, b2, bufB, N);

    // 5) two-stage mean-pool + head  (fill covers ALL G*64 sums — round-8 bug fix)
    k_fill<<<ceil_div_ll(G * 64, B), B, 0, stream>>>(sums, G * 64, 0.0f);
    k_pool1<<<1024, 256, 0, stream>>>(bufB, bat, sums, N);
    k_head<<<G, 64, 0, stream>>>(sums, bat, Wfc, bfc, out, N);
}